// Round 7
// baseline (593.366 us; speedup 1.0000x reference)
//
#include <hip/hip_runtime.h>

typedef unsigned short u16;
typedef unsigned short u16x8 __attribute__((ext_vector_type(8)));
typedef __bf16 bf16x8 __attribute__((ext_vector_type(8)));
typedef float f32x4 __attribute__((ext_vector_type(4)));

// B=2, T=2048, N_EMBD=2048, D_INNER=4096, N_HEADS=32, HEAD_DIM=128, D_STATE=128,
// PROJ=8480 (= 8192 main + 288 tail), CHUNK=64, n_chunks=32. External fp32; staging bf16.
// proj row: [0,4096) gate | [4096,8192) ssm_in | [8192,8224) dt | [8224,8352) B | [8352,8480) C

__device__ __forceinline__ float bf2f(u16 u) {
    union { unsigned int i; float f; } v; v.i = ((unsigned int)u) << 16; return v.f;
}
__device__ __forceinline__ u16 f2bf(float f) {
    unsigned int u = __float_as_uint(f);
    u += 0x7fffu + ((u >> 16) & 1u);   // RNE
    return (u16)(u >> 16);
}
__device__ __forceinline__ bf16x8 ld8(const u16* p) {
    return __builtin_bit_cast(bf16x8, *reinterpret_cast<const u16x8*>(p));
}
__device__ __forceinline__ void load_lds16(const u16* g, u16* l) {
    __builtin_amdgcn_global_load_lds(
        (const __attribute__((address_space(1))) unsigned int*)g,
        (__attribute__((address_space(3))) unsigned int*)l, 16, 0, 0);
}
__device__ __forceinline__ float fexp(float x) { return __expf(x); }
__device__ __forceinline__ float frcp(float x) { return __builtin_amdgcn_rcpf(x); }

// ---------------- K1: RMSNorm (fp32 in, bf16 out) ----------------
__global__ __launch_bounds__(256) void k_rmsnorm(const float* __restrict__ x,
                                                 const float* __restrict__ scale,
                                                 u16* __restrict__ h) {
    int row = blockIdx.x, tid = threadIdx.x;
    const float4* xr = reinterpret_cast<const float4*>(x + (size_t)row * 2048);
    float4 v0 = xr[tid], v1 = xr[tid + 256];
    float ss = v0.x*v0.x + v0.y*v0.y + v0.z*v0.z + v0.w*v0.w
             + v1.x*v1.x + v1.y*v1.y + v1.z*v1.z + v1.w*v1.w;
#pragma unroll
    for (int off = 32; off > 0; off >>= 1) ss += __shfl_down(ss, off, 64);
    __shared__ float red[4];
    if ((tid & 63) == 0) red[tid >> 6] = ss;
    __syncthreads();
    float r = rsqrtf((red[0] + red[1] + red[2] + red[3]) * (1.f / 2048.f) + 1e-6f);
    const float4* sc = reinterpret_cast<const float4*>(scale);
    float4 s0 = sc[tid], s1 = sc[tid + 256];
    ushort4 o0, o1;
    o0.x = f2bf(v0.x * r * s0.x); o0.y = f2bf(v0.y * r * s0.y);
    o0.z = f2bf(v0.z * r * s0.z); o0.w = f2bf(v0.w * r * s0.w);
    o1.x = f2bf(v1.x * r * s1.x); o1.y = f2bf(v1.y * r * s1.y);
    o1.z = f2bf(v1.z * r * s1.z); o1.w = f2bf(v1.w * r * s1.w);
    ushort4* hr = reinterpret_cast<ushort4*>(h + (size_t)row * 2048);
    hr[tid] = o0; hr[tid + 256] = o1;
}

// ---------------- K0: transpose-cast weights fp32 [K][N] -> bf16 [Npad][K] ----------------
__global__ __launch_bounds__(256) void k_wcast(const float* __restrict__ W,
                                               u16* __restrict__ Wt,
                                               int K, int N) {
    __shared__ u16 Ts[64][72];
    int n0 = blockIdx.x * 64, k0 = blockIdx.y * 64;
    int t = threadIdx.x;
    int jl = (t & 15) * 4;
#pragma unroll
    for (int s = 0; s < 4; ++s) {
        int kl = s * 16 + (t >> 4);
        if (n0 + jl + 4 <= N) {
            float4 v = *reinterpret_cast<const float4*>(W + (size_t)(k0 + kl) * N + n0 + jl);
            Ts[kl][jl] = f2bf(v.x); Ts[kl][jl + 1] = f2bf(v.y);
            Ts[kl][jl + 2] = f2bf(v.z); Ts[kl][jl + 3] = f2bf(v.w);
        } else {
#pragma unroll
            for (int e = 0; e < 4; ++e)
                Ts[kl][jl + e] = (n0 + jl + e < N) ? f2bf(W[(size_t)(k0 + kl) * N + n0 + jl + e]) : (u16)0;
        }
    }
    __syncthreads();
    int nl = t >> 2, kl0 = (t & 3) * 16;
    u16 tmp[16];
#pragma unroll
    for (int e = 0; e < 16; ++e) tmp[e] = Ts[kl0 + e][nl];
    u16* dst = Wt + (size_t)(n0 + nl) * K + k0 + kl0;
    *reinterpret_cast<uint4*>(dst) = *reinterpret_cast<uint4*>(tmp);
    *reinterpret_cast<uint4*>(dst + 8) = *reinterpret_cast<uint4*>(tmp + 8);
}

// ---------------- K2: 128x128 MFMA GEMM (narrow proj tail) ----------------
// MAP=1: nb=bid%nbt, mb=bid/nbt. Output: C[gm*ldc + ncoff + gn], gn < Nw.
template <bool BF16_OUT, int MAP>
__global__ __launch_bounds__(256) void k_gemm128(const u16* __restrict__ A,
                                                 const u16* __restrict__ Bt,
                                                 u16* __restrict__ Cb,
                                                 float* __restrict__ Cf,
                                                 const float* __restrict__ resid,
                                                 int M, int Nw, int ldc, int ncoff,
                                                 int K, int nbt) {
    __shared__ u16 As[8192];
    __shared__ u16 Bs[8192];
    int bid = blockIdx.x;
    int mb, nb;
    if (MAP == 0) {
        int mt = M >> 7;
        int grp = mt * 8;
        int g = bid / grp, l = bid % grp;
        nb = g * 8 + (l & 7); mb = l >> 3;
        if (nb * 128 >= Nw) return;
    } else {
        nb = bid % nbt; mb = bid / nbt;
    }
    int m0 = mb * 128, n0 = nb * 128;

    int t = threadIdx.x, lane = t & 63, w = t >> 6;
    int row = t >> 2, kc = (t & 3) * 8;
    int wm = (w >> 1) * 64, wn = (w & 1) * 64;
    int r = lane & 15, q = lane >> 4;

    f32x4 acc[4][4];
#pragma unroll
    for (int a = 0; a < 4; ++a)
#pragma unroll
        for (int b = 0; b < 4; ++b) acc[a][b] = (f32x4){0.f, 0.f, 0.f, 0.f};

    const u16* ga0 = A + (size_t)(m0 + row) * K + kc;
    const u16* ga1 = A + (size_t)(m0 + 64 + row) * K + kc;
    const u16* gb0 = Bt + (size_t)(ncoff + n0 + row) * K + kc;
    const u16* gb1 = Bt + (size_t)(ncoff + n0 + 64 + row) * K + kc;

    for (int k0 = 0; k0 < K; k0 += 64) {
        load_lds16(ga0 + k0,      As + w * 512);
        load_lds16(ga1 + k0,      As + 2048 + w * 512);
        load_lds16(gb0 + k0,      Bs + w * 512);
        load_lds16(gb1 + k0,      Bs + 2048 + w * 512);
        load_lds16(ga0 + k0 + 32, As + 4096 + w * 512);
        load_lds16(ga1 + k0 + 32, As + 4096 + 2048 + w * 512);
        load_lds16(gb0 + k0 + 32, Bs + 4096 + w * 512);
        load_lds16(gb1 + k0 + 32, Bs + 4096 + 2048 + w * 512);
        __syncthreads();
#pragma unroll
        for (int h = 0; h < 2; ++h) {
            bf16x8 af[4], bf[4];
#pragma unroll
            for (int mi = 0; mi < 4; ++mi) af[mi] = ld8(&As[h * 4096 + (wm + mi * 16 + r) * 32 + q * 8]);
#pragma unroll
            for (int ni = 0; ni < 4; ++ni) bf[ni] = ld8(&Bs[h * 4096 + (wn + ni * 16 + r) * 32 + q * 8]);
#pragma unroll
            for (int mi = 0; mi < 4; ++mi)
#pragma unroll
                for (int ni = 0; ni < 4; ++ni)
                    acc[mi][ni] = __builtin_amdgcn_mfma_f32_16x16x32_bf16(af[mi], bf[ni], acc[mi][ni], 0, 0, 0);
        }
        __syncthreads();
    }
#pragma unroll
    for (int mi = 0; mi < 4; ++mi)
#pragma unroll
        for (int ni = 0; ni < 4; ++ni) {
            int lgn = n0 + wn + ni * 16 + r;
            if (lgn < Nw) {
#pragma unroll
                for (int rg = 0; rg < 4; ++rg) {
                    int gm = m0 + wm + mi * 16 + q * 4 + rg;
                    float vv = acc[mi][ni][rg];
                    if (BF16_OUT) {
                        Cb[(size_t)gm * ldc + ncoff + lgn] = f2bf(vv);
                    } else {
                        if (resid) vv += resid[(size_t)gm * ldc + ncoff + lgn];
                        Cf[(size_t)gm * ldc + ncoff + lgn] = vv;
                    }
                }
            }
        }
}

// ---------------- K2new: 256x256 8-phase GEMM — R2/R5-PROVEN sync structure ----
// 512 thr = 8 waves (2M x 4N); per-wave 128x64 out; BK=64; LDS 128 KiB double-buffered.
// LDS swizzle: 16B-chunk c at row rw holds logical chunk c ^ (rw & 7) (both sides).
// Stage schedule per tile kt (harness-verified R2+R5, 141 µs; R6 full-tile-ahead
// regressed to 152 — bursty VMEM issue, reverted): p0: A1(kt+1) | p2: B0(kt+2)
//   | p3: B1(kt+2), A0(kt+2), barrier, MFMA, vmcnt(6).
// Split-K: ks = swz / tiles; A/B advance ks*Kl cols; f32 partial at Cf + ks*M*Nout;
// ks==0 partial adds resid. lda = row stride of A/Bt (out-proj: lda=4096, Kl=2048).
template <bool F32OUT>
__global__ __launch_bounds__(512, 2) void k_gemm256(const u16* __restrict__ A,
                                                    const u16* __restrict__ Bt,
                                                    u16* __restrict__ Cb,
                                                    float* __restrict__ Cf,
                                                    const float* __restrict__ resid,
                                                    int M, int Nout, int ldc,
                                                    int lda, int Kl) {
    __shared__ u16 lds[65536];          // A: [2buf][2half][128][64] at 0; B same at 32768
    const int nkt = Kl >> 6;
    int mt = M >> 8;
    int bid = blockIdx.x;
    int swz = (bid & 7) * ((int)gridDim.x >> 3) + (bid >> 3);   // XCD-contiguous (grid%8==0)
    int tiles = mt * (Nout >> 8);
    int tp = swz % tiles, ks = swz / tiles;
    int mb = tp % mt, nb = tp / mt;
    int m0 = mb << 8, n0 = nb << 8;
    int koff = ks * Kl;

    int t = threadIdx.x;
    int ln = t & 63, w = t >> 6;
    int wm = w >> 2, wn = w & 3;
    int r = ln & 15, q = ln >> 4;
    int xq = (q << 3) ^ ((r & 7) << 3);          // swizzled chunk offset within row

    // staging: lane covers row (w*8 + ln/8) of the region; source chunk pre-swizzled
    int rr = ln >> 3;
    int cc8 = ((ln & 7) ^ rr) << 3;
    const u16* Ag = A + (size_t)(m0 + w * 8 + rr) * lda + koff + cc8;
    const u16* Bg = Bt + (size_t)(n0 + w * 8 + rr) * lda + koff + cc8;
    u16* ldsw = lds + (w << 9);
    const size_t R64 = (size_t)lda * 64;     // +64 rows
    const size_t R128 = (size_t)lda * 128;   // +128 rows

    f32x4 acc[8][4];
#pragma unroll
    for (int a = 0; a < 8; ++a)
#pragma unroll
        for (int b = 0; b < 4; ++b) acc[a][b] = (f32x4){0.f, 0.f, 0.f, 0.f};

    auto stageA = [&](int ti, int h) {
        if (ti >= nkt) return;
        const u16* g = Ag + ((size_t)ti << 6) + (h ? R128 : (size_t)0);
        u16* d = ldsw + ((ti & 1) << 14) + (h << 13);
        load_lds16(g, d);
        load_lds16(g + R64, d + 4096);
    };
    auto stageB = [&](int ti, int h) {
        if (ti >= nkt) return;
        const u16* g = Bg + ((size_t)ti << 6) + (h ? R128 : (size_t)0);
        u16* d = ldsw + 32768 + ((ti & 1) << 14) + (h << 13);
        load_lds16(g, d);
        load_lds16(g + R64, d + 4096);
    };

    // prologue: S[0..6] = A0(0) B0(0) B1(0) A1(0) A0(1) B0(1) B1(1); vmcnt(6) lands tile 0.
    stageA(0, 0); stageB(0, 0); stageB(0, 1); stageA(0, 1);
    stageA(1, 0); stageB(1, 0); stageB(1, 1);
    asm volatile("s_waitcnt vmcnt(6)" ::: "memory");
    __builtin_amdgcn_s_barrier();
    asm volatile("" ::: "memory");

    bf16x8 aF[4][2], bLo[2][2], bHi[2][2];

    for (int kt = 0; kt < nkt; ++kt) {
        const u16* Ah = lds + ((kt & 1) << 14) + (wm << 13);
        const u16* Bh = lds + 32768 + ((kt & 1) << 14) + ((wn >> 1) << 13) + ((wn & 1) << 12);

        // ---- phase 0: read A-low (8) + B-low (4); stage A1(kt+1); mfma Mlo x Nlo
#pragma unroll
        for (int mi = 0; mi < 4; ++mi)
#pragma unroll
            for (int ks2 = 0; ks2 < 2; ++ks2)
                aF[mi][ks2] = ld8(Ah + (mi * 16 + r) * 64 + (xq ^ (ks2 << 5)));
#pragma unroll
        for (int ni = 0; ni < 2; ++ni)
#pragma unroll
            for (int ks2 = 0; ks2 < 2; ++ks2)
                bLo[ni][ks2] = ld8(Bh + (ni * 16 + r) * 64 + (xq ^ (ks2 << 5)));
        stageA(kt + 1, 1);
        asm volatile("" ::: "memory");
        __builtin_amdgcn_s_barrier();
        asm volatile("s_waitcnt lgkmcnt(0)" ::: "memory");
        __builtin_amdgcn_s_setprio(1);
#pragma unroll
        for (int mi = 0; mi < 4; ++mi)
#pragma unroll
            for (int ni = 0; ni < 2; ++ni)
#pragma unroll
                for (int ks2 = 0; ks2 < 2; ++ks2)
                    acc[mi][ni] = __builtin_amdgcn_mfma_f32_16x16x32_bf16(aF[mi][ks2], bLo[ni][ks2], acc[mi][ni], 0, 0, 0);
        __builtin_amdgcn_s_setprio(0);
        asm volatile("" ::: "memory");
        __builtin_amdgcn_s_barrier();
        asm volatile("" ::: "memory");

        // ---- phase 1: read B-high (4); no stage; mfma Mlo x Nhi
#pragma unroll
        for (int ni = 0; ni < 2; ++ni)
#pragma unroll
            for (int ks2 = 0; ks2 < 2; ++ks2)
                bHi[ni][ks2] = ld8(Bh + ((ni + 2) * 16 + r) * 64 + (xq ^ (ks2 << 5)));
        asm volatile("" ::: "memory");
        __builtin_amdgcn_s_barrier();
        asm volatile("s_waitcnt lgkmcnt(0)" ::: "memory");
        __builtin_amdgcn_s_setprio(1);
#pragma unroll
        for (int mi = 0; mi < 4; ++mi)
#pragma unroll
            for (int ni = 0; ni < 2; ++ni)
#pragma unroll
                for (int ks2 = 0; ks2 < 2; ++ks2)
                    acc[mi][ni + 2] = __builtin_amdgcn_mfma_f32_16x16x32_bf16(aF[mi][ks2], bHi[ni][ks2], acc[mi][ni + 2], 0, 0, 0);
        __builtin_amdgcn_s_setprio(0);
        asm volatile("" ::: "memory");
        __builtin_amdgcn_s_barrier();
        asm volatile("" ::: "memory");

        // ---- phase 2: read A-high (8); stage B0(kt+2); mfma Mhi x Nhi
#pragma unroll
        for (int mi = 0; mi < 4; ++mi)
#pragma unroll
            for (int ks2 = 0; ks2 < 2; ++ks2)
                aF[mi][ks2] = ld8(Ah + ((mi + 4) * 16 + r) * 64 + (xq ^ (ks2 << 5)));
        stageB(kt + 2, 0);
        asm volatile("" ::: "memory");
        __builtin_amdgcn_s_barrier();
        asm volatile("s_waitcnt lgkmcnt(0)" ::: "memory");
        __builtin_amdgcn_s_setprio(1);
#pragma unroll
        for (int mi = 0; mi < 4; ++mi)
#pragma unroll
            for (int ni = 0; ni < 2; ++ni)
#pragma unroll
                for (int ks2 = 0; ks2 < 2; ++ks2)
                    acc[mi + 4][ni + 2] = __builtin_amdgcn_mfma_f32_16x16x32_bf16(aF[mi][ks2], bHi[ni][ks2], acc[mi + 4][ni + 2], 0, 0, 0);
        __builtin_amdgcn_s_setprio(0);
        asm volatile("" ::: "memory");
        __builtin_amdgcn_s_barrier();
        asm volatile("" ::: "memory");

        // ---- phase 3: no reads; stage B1(kt+2) + A0(kt+2); barrier; mfma Mhi x Nlo; vmcnt(6|0)
        stageB(kt + 2, 1);
        stageA(kt + 2, 0);
        asm volatile("" ::: "memory");
        __builtin_amdgcn_s_barrier();
        __builtin_amdgcn_s_setprio(1);
#pragma unroll
        for (int mi = 0; mi < 4; ++mi)
#pragma unroll
            for (int ni = 0; ni < 2; ++ni)
#pragma unroll
                for (int ks2 = 0; ks2 < 2; ++ks2)
                    acc[mi + 4][ni] = __builtin_amdgcn_mfma_f32_16x16x32_bf16(aF[mi][ks2], bLo[ni][ks2], acc[mi + 4][ni], 0, 0, 0);
        __builtin_amdgcn_s_setprio(0);
        if (kt + 2 < nkt) { asm volatile("s_waitcnt vmcnt(6)" ::: "memory"); }
        else              { asm volatile("s_waitcnt vmcnt(0)" ::: "memory"); }
        __builtin_amdgcn_s_barrier();
        asm volatile("" ::: "memory");
    }

    // epilogue: bf16 store (row stride ldc) or f32 split-K partial (dense Nout, +resid at ks==0)
#pragma unroll
    for (int mi = 0; mi < 8; ++mi)
#pragma unroll
        for (int ni = 0; ni < 4; ++ni) {
            int gn = n0 + wn * 64 + ni * 16 + r;
            if (gn < Nout) {
#pragma unroll
                for (int rg = 0; rg < 4; ++rg) {
                    int gm = m0 + wm * 128 + mi * 16 + q * 4 + rg;
                    if (F32OUT) {
                        float vv = acc[mi][ni][rg];
                        if (ks == 0 && resid) vv += resid[(size_t)gm * Nout + gn];
                        Cf[(size_t)ks * M * Nout + (size_t)gm * Nout + gn] = vv;
                    } else {
                        Cb[(size_t)gm * ldc + gn] = f2bf(acc[mi][ni][rg]);
                    }
                }
            }
        }
}

// ---------------- K9: out = P0 + P1 (split-K reduce; resid already in P0) ----------------
__global__ __launch_bounds__(256) void k_addred(const float* __restrict__ P0,
                                                const float* __restrict__ P1,
                                                float* __restrict__ out) {
    const float4* a = reinterpret_cast<const float4*>(P0);
    const float4* b = reinterpret_cast<const float4*>(P1);
    float4* o = reinterpret_cast<float4*>(out);
    for (int k = blockIdx.x * 256 + threadIdx.x; k < 2097152; k += 524288) {
        float4 aa = a[k], bb = b[k];
        float4 r;
        r.x = aa.x + bb.x; r.y = aa.y + bb.y;
        r.z = aa.z + bb.z; r.w = aa.w + bb.w;
        o[k] = r;
    }
}

// ---------------- K4: dt=softplus, per-chunk inclusive cumsum of A*dt ----------------
__global__ __launch_bounds__(64) void k_dt(const u16* __restrict__ proj,
                                           const float* __restrict__ A_log,
                                           const float* __restrict__ dt_bias,
                                           float* __restrict__ dt,
                                           float* __restrict__ cumla) {
    int bid = blockIdx.x;
    int b = bid >> 10, hh = (bid >> 5) & 31, c = bid & 31;
    int j = threadIdx.x;
    int t = c * 64 + j;
    float z = bf2f(proj[(size_t)(b * 2048 + t) * 8480 + 8192 + hh]) + dt_bias[hh];
    float dtv = (z > 20.f) ? z : log1pf(fexp(z));
    float v = -fexp(A_log[hh]) * dtv;
#pragma unroll
    for (int off = 1; off < 64; off <<= 1) {
        float pv = __shfl_up(v, off, 64);
        if (j >= off) v += pv;
    }
    int base = ((b * 32 + hh) * 32 + c) * 64;
    dt[base + j] = dtv;
    cumla[base + j] = v;
}

// ---------------- K5: intra-chunk, conv+SiLU fused; B/C fragments direct from global ----------------
__global__ __launch_bounds__(256) void k_intra(const u16* __restrict__ proj,
                                               const float* __restrict__ dt,
                                               const float* __restrict__ cumla,
                                               const float* __restrict__ cw,
                                               const float* __restrict__ cb,
                                               const float* __restrict__ Dv,
                                               u16* __restrict__ ybuf,
                                               u16* __restrict__ states) {
    __shared__ u16 Xt[128][72];
    __shared__ u16 Bt[128][72];
    __shared__ union {
        u16 Ms[64][72];                                   // step1 -> step2
        struct { float cwl[4][128]; float cbl[128]; } cv; // staging only
    } sh;
    __shared__ float dts[64], clas[64];
    int bid = blockIdx.x;
    int b = bid >> 10, c = (bid >> 5) & 31, hh = bid & 31;
    int tid = threadIdx.x, lane = tid & 63, w = tid >> 6;
    int r = lane & 15, q = lane >> 4;
    int t0 = b * 2048 + c * 64;
    int sbase = ((b * 32 + hh) * 32 + c) * 64;

    if (tid < 64) { dts[tid] = dt[sbase + tid]; clas[tid] = cumla[sbase + tid]; }
    if (tid < 128) {
        sh.cv.cbl[tid] = cb[hh * 128 + tid];
#pragma unroll
        for (int k = 0; k < 4; ++k) sh.cv.cwl[k][tid] = cw[k * 4096 + hh * 128 + tid];
    }
    __syncthreads();

    // conv(4)+bias+SiLU -> Xt[p][j]; weighted B^T -> Bt[p][j]  (B rows read from global/L2)
    {
        int j = tid & 63;
        float wj = fexp(clas[63] - clas[j]) * dts[j];
        for (int g = tid >> 6; g < 16; g += 4) {
            int p0 = g * 8;
            u16 tb[8];
            *reinterpret_cast<uint4*>(tb) =
                *reinterpret_cast<const uint4*>(proj + (size_t)(t0 + j) * 8480 + 8224 + p0);
            float xv[8];
#pragma unroll
            for (int e = 0; e < 8; ++e) xv[e] = sh.cv.cbl[p0 + e];
#pragma unroll
            for (int kk = 0; kk < 4; ++kk) {
                int tl = c * 64 + j - 3 + kk;
                if (tl >= 0) {
                    u16 srow[8];
                    *reinterpret_cast<uint4*>(srow) =
                        *reinterpret_cast<const uint4*>(proj + (size_t)(b * 2048 + tl) * 8480 + 4096 + hh * 128 + p0);
#pragma unroll
                    for (int e = 0; e < 8; ++e) xv[e] += sh.cv.cwl[kk][p0 + e] * bf2f(srow[e]);
                }
            }
#pragma unroll
            for (int e = 0; e < 8; ++e) {
                float s = xv[e] * frcp(1.f + fexp(-xv[e]));
                Xt[p0 + e][j] = f2bf(s);
                Bt[p0 + e][j] = f2bf(wj * bf2f(tb[e]));
            }
        }
    }
    __syncthreads();

    // step1: M = decay(C·B^T); C and B fragments direct from global (32-head L2 reuse)
    {
        const u16* crow = proj + (size_t)(t0 + w * 16 + r) * 8480 + 8352;
        bf16x8 af[4];
#pragma unroll
        for (int k = 0; k < 4; ++k) af[k] = ld8(crow + k * 32 + q * 8);
#pragma unroll
        for (int tj = 0; tj < 4; ++tj) {
            const u16* brow = proj + (size_t)(t0 + tj * 16 + r) * 8480 + 8224;
            f32x4 acc = (f32x4){0.f, 0.f, 0.f, 0.f};
#pragma unroll
            for (int k = 0; k < 4; ++k)
                acc = __builtin_amdgcn_mfma_f32_16x16x32_bf16(af[k], ld8(brow + k * 32 + q * 8), acc, 0, 0, 0);
            int j = tj * 16 + r;
            float dj = dts[j], cj = clas[j];
#pragma unroll
            for (int rg = 0; rg < 4; ++rg) {
                int i = w * 16 + q * 4 + rg;
                float m = (j <= i) ? acc[rg] * fexp(clas[i] - cj) * dj : 0.f;
                sh.Ms[i][j] = f2bf(m);
            }
        }
    }
    __syncthreads();

    // step2: Y = M @ X + D*X
    {
        bf16x8 af[2];
#pragma unroll
        for (int k = 0; k < 2; ++k) af[k] = ld8(&sh.Ms[w * 16 + r][k * 32 + q * 8]);
#pragma unroll
        for (int tj = 0; tj < 8; ++tj) {
            f32x4 acc = (f32x4){0.f, 0.f, 0.f, 0.f};
#pragma unroll
            for (int k = 0; k < 2; ++k)
                acc = __builtin_amdgcn_mfma_f32_16x16x32_bf16(af[k], ld8(&Xt[tj * 16 + r][k * 32 + q * 8]), acc, 0, 0, 0);
            int p = tj * 16 + r;
            float dv = Dv[hh * 128 + p];
#pragma unroll
            for (int rg = 0; rg < 4; ++rg) {
                int i = w * 16 + q * 4 + rg;
                float v = acc[rg] + dv * bf2f(Xt[p][i]);
                ybuf[(size_t)(t0 + i) * 4096 + hh * 128 + p] = f2bf(v);
            }
        }
    }

    // step3: St[p][n] = sum_j Xt[p][j]*Bt[n][j]
    size_t sb = ((size_t)((b * 32 + hh) * 32 + c)) * 16384;
#pragma unroll
    for (int th = 0; th < 2; ++th) {
        int ti = w + th * 4;
        bf16x8 af[2];
#pragma unroll
        for (int k = 0; k < 2; ++k) af[k] = ld8(&Xt[ti * 16 + r][k * 32 + q * 8]);
#pragma unroll
        for (int tj = 0; tj < 8; ++tj) {
            f32x4 acc = (f32x4){0.f, 0.f, 0.f, 0.f};
#pragma unroll
            for (int k = 0; k < 2; ++k)
                acc = __builtin_amdgcn_mfma_f32_16x16x32_bf16(af[k], ld8(&Bt[tj * 16 + r][k * 32 + q * 8]), acc, 0, 0, 0);
            int n = tj * 16 + r;
#pragma unroll
            for (int rg = 0; rg < 4; ++rg) {
                int p = ti * 16 + q * 4 + rg;
                states[sb + p * 128 + n] = f2bf(acc[rg]);
            }
        }
    }
}

// ---------------- K6: inter-chunk sequential scan, 4 elems/thread (8B vectors) ----------------
__global__ __launch_bounds__(256) void k_scan(u16* __restrict__ states,
                                              const float* __restrict__ cumla) {
    int gid = blockIdx.x * 256 + threadIdx.x;   // 262144 total
    int bh = gid >> 12;
    int q4 = (gid & 4095) * 4;
    size_t base = (size_t)bh * 32 * 16384 + q4;
    float s0 = 0.f, s1 = 0.f, s2 = 0.f, s3 = 0.f;
    for (int c = 0; c < 32; ++c) {
        float cd = fexp(cumla[(bh * 32 + c) * 64 + 63]);
        size_t idx = base + (size_t)c * 16384;
        ushort4 v = *reinterpret_cast<ushort4*>(states + idx);
        float l0 = bf2f(v.x), l1 = bf2f(v.y), l2 = bf2f(v.z), l3 = bf2f(v.w);
        ushort4 o; o.x = f2bf(s0); o.y = f2bf(s1); o.z = f2bf(s2); o.w = f2bf(s3);
        *reinterpret_cast<ushort4*>(states + idx) = o;
        s0 = cd * s0 + l0; s1 = cd * s1 + l1; s2 = cd * s2 + l2; s3 = cd * s3 + l3;
    }
}

// ---------------- K7: Y = ybuf + exp(cla)*C@S, SiLU gate ----------------
__global__ __launch_bounds__(256) void k_inter(const u16* __restrict__ proj,
                                               const u16* __restrict__ states,
                                               const float* __restrict__ cumla,
                                               const u16* __restrict__ ybuf,
                                               u16* __restrict__ ygated) {
    __shared__ u16 Ss[128][136];
    __shared__ float clav[64];
    int bid = blockIdx.x;
    int b = bid >> 10, c = (bid >> 5) & 31, hh = bid & 31;
    int tid = threadIdx.x, lane = tid & 63, w = tid >> 6;
    int r = lane & 15, q = lane >> 4;
    int t0 = b * 2048 + c * 64;
    int sbase = ((b * 32 + hh) * 32 + c) * 64;
    size_t sb = ((size_t)((b * 32 + hh) * 32 + c)) * 16384;

    if (tid < 64) clav[tid] = fexp(cumla[sbase + tid]);
    for (int e = tid; e < 2048; e += 256) {
        int p = e >> 4, n8 = (e & 15) * 8;
        *reinterpret_cast<uint4*>(&Ss[p][n8]) =
            *reinterpret_cast<const uint4*>(states + sb + p * 128 + n8);
    }
    __syncthreads();

    const u16* crow = proj + (size_t)(t0 + w * 16 + r) * 8480 + 8352;
    bf16x8 af[4];
#pragma unroll
    for (int k = 0; k < 4; ++k) af[k] = ld8(crow + k * 32 + q * 8);
#pragma unroll
    for (int tj = 0; tj < 8; ++tj) {
        f32x4 acc = (f32x4){0.f, 0.f, 0.f, 0.f};
#pragma unroll
        for (int k = 0; k < 4; ++k)
            acc = __builtin_amdgcn_mfma_f32_16x16x32_bf16(af[k], ld8(&Ss[tj * 16 + r][k * 32 + q * 8]), acc, 0, 0, 0);
        int p = tj * 16 + r;
        int ch = hh * 128 + p;
#pragma unroll
        for (int rg = 0; rg < 4; ++rg) {
            int i = w * 16 + q * 4 + rg;
            size_t td = (size_t)(t0 + i) * 4096 + ch;
            float v = clav[i] * acc[rg] + bf2f(ybuf[td]);
            float g = bf2f(proj[(size_t)(t0 + i) * 8480 + ch]);
            ygated[td] = f2bf(v * (g * frcp(1.f + fexp(-g))));
        }
    }
}

extern "C" void kernel_launch(void* const* d_in, const int* in_sizes, int n_in,
                              void* d_out, int out_size, void* d_ws, size_t ws_size,
                              hipStream_t stream) {
    const float* x          = (const float*)d_in[0];
    const float* norm_scale = (const float*)d_in[1];
    const float* in_proj_w  = (const float*)d_in[2];
    const float* conv_w     = (const float*)d_in[3];
    const float* conv_b     = (const float*)d_in[4];
    const float* A_log      = (const float*)d_in[5];
    const float* dt_bias    = (const float*)d_in[6];
    const float* Dv         = (const float*)d_in[7];
    const float* out_w      = (const float*)d_in[8];
    float* out = (float*)d_out;

    char* ws = (char*)d_ws;
    u16*   states = (u16*)(ws);               // [0,67.1M); h aliases [0,16.8M), wbt [16.8M,52.5M)
    u16*   h      = (u16*)(ws);
    u16*   wbt    = (u16*)(ws + 16777216);    // 8704x2048 bf16 (rows 8480..8703 zero)
    float* parts  = (float*)(ws);             // split-K partials 2x 4096x2048 f32 (after k_inter)
    u16*   proj   = (u16*)(ws + 67108864);    // 69,468,160
    u16*   owt    = (u16*)(ws + 136577024);   // 2048x4096 bf16
    u16*   ybuf   = (u16*)(ws + 170131456);   // 33,554,432 (also ygated)
    float* dt     = (float*)(ws + 203685888);
    float* cumla  = (float*)(ws + 204210176);

    k_rmsnorm<<<4096, 256, 0, stream>>>(x, norm_scale, h);
    k_wcast<<<dim3(136, 32), 256, 0, stream>>>(in_proj_w, wbt, 2048, 8480);
    // proj tail: cols 8192..8480 (dt+B+C), 96 blocks of 128x128
    k_gemm128<true, 1><<<96, 256, 0, stream>>>(h, wbt, proj, nullptr, nullptr,
                                               4096, 288, 8480, 8192, 2048, 3);
    // proj main: cols 0..8192, 512 blocks of 256x256 = exactly 2 rounds; ldc=8480
    k_gemm256<false><<<512, 512, 0, stream>>>(h, wbt, proj, nullptr, nullptr,
                                              4096, 8192, 8480, 2048, 2048);
    k_dt<<<2048, 64, 0, stream>>>(proj, A_log, dt_bias, dt, cumla);
    k_intra<<<2048, 256, 0, stream>>>(proj, dt, cumla, conv_w, conv_b, Dv, ybuf, states);
    k_scan<<<1024, 256, 0, stream>>>(states, cumla);
    k_inter<<<2048, 256, 0, stream>>>(proj, states, cumla, ybuf, ybuf);
    k_wcast<<<dim3(32, 64), 256, 0, stream>>>(out_w, owt, 4096, 2048);
    // out-proj: split-K=2, 128 tiles x 2 = 256 blocks = 1 round; x folded into ks=0 partial
    k_gemm256<true><<<256, 512, 0, stream>>>(ybuf, owt, nullptr, parts, x,
                                             4096, 2048, 2048, 4096, 2048);
    k_addred<<<2048, 256, 0, stream>>>(parts, parts + 8388608, out);
}

// Round 9
// 525.338 us; speedup vs baseline: 1.1295x; 1.1295x over previous
//
#include <hip/hip_runtime.h>

typedef unsigned short u16;
typedef unsigned short u16x8 __attribute__((ext_vector_type(8)));
typedef __bf16 bf16x8 __attribute__((ext_vector_type(8)));
typedef float f32x4 __attribute__((ext_vector_type(4)));

// B=2, T=2048, N_EMBD=2048, D_INNER=4096, N_HEADS=32, HEAD_DIM=128, D_STATE=128,
// PROJ=8480 (= 8192 main + 288 tail), CHUNK=64, n_chunks=32. External fp32; staging bf16.
// proj row: [0,4096) gate | [4096,8192) ssm_in | [8192,8224) dt | [8224,8352) B | [8352,8480) C

__device__ __forceinline__ float bf2f(u16 u) {
    union { unsigned int i; float f; } v; v.i = ((unsigned int)u) << 16; return v.f;
}
__device__ __forceinline__ u16 f2bf(float f) {
    unsigned int u = __float_as_uint(f);
    u += 0x7fffu + ((u >> 16) & 1u);   // RNE
    return (u16)(u >> 16);
}
__device__ __forceinline__ bf16x8 ld8(const u16* p) {
    return __builtin_bit_cast(bf16x8, *reinterpret_cast<const u16x8*>(p));
}
__device__ __forceinline__ void load_lds16(const u16* g, u16* l) {
    __builtin_amdgcn_global_load_lds(
        (const __attribute__((address_space(1))) unsigned int*)g,
        (__attribute__((address_space(3))) unsigned int*)l, 16, 0, 0);
}
__device__ __forceinline__ float fexp(float x) { return __expf(x); }
__device__ __forceinline__ float frcp(float x) { return __builtin_amdgcn_rcpf(x); }

// ---------------- K1: RMSNorm (fp32 in, bf16 out) ----------------
__global__ __launch_bounds__(256) void k_rmsnorm(const float* __restrict__ x,
                                                 const float* __restrict__ scale,
                                                 u16* __restrict__ h) {
    int row = blockIdx.x, tid = threadIdx.x;
    const float4* xr = reinterpret_cast<const float4*>(x + (size_t)row * 2048);
    float4 v0 = xr[tid], v1 = xr[tid + 256];
    float ss = v0.x*v0.x + v0.y*v0.y + v0.z*v0.z + v0.w*v0.w
             + v1.x*v1.x + v1.y*v1.y + v1.z*v1.z + v1.w*v1.w;
#pragma unroll
    for (int off = 32; off > 0; off >>= 1) ss += __shfl_down(ss, off, 64);
    __shared__ float red[4];
    if ((tid & 63) == 0) red[tid >> 6] = ss;
    __syncthreads();
    float r = rsqrtf((red[0] + red[1] + red[2] + red[3]) * (1.f / 2048.f) + 1e-6f);
    const float4* sc = reinterpret_cast<const float4*>(scale);
    float4 s0 = sc[tid], s1 = sc[tid + 256];
    ushort4 o0, o1;
    o0.x = f2bf(v0.x * r * s0.x); o0.y = f2bf(v0.y * r * s0.y);
    o0.z = f2bf(v0.z * r * s0.z); o0.w = f2bf(v0.w * r * s0.w);
    o1.x = f2bf(v1.x * r * s1.x); o1.y = f2bf(v1.y * r * s1.y);
    o1.z = f2bf(v1.z * r * s1.z); o1.w = f2bf(v1.w * r * s1.w);
    ushort4* hr = reinterpret_cast<ushort4*>(h + (size_t)row * 2048);
    hr[tid] = o0; hr[tid + 256] = o1;
}

// ---------------- K0: transpose-cast weights fp32 [K][N] -> bf16 [Npad][K] ----------------
__global__ __launch_bounds__(256) void k_wcast(const float* __restrict__ W,
                                               u16* __restrict__ Wt,
                                               int K, int N) {
    __shared__ u16 Ts[64][72];
    int n0 = blockIdx.x * 64, k0 = blockIdx.y * 64;
    int t = threadIdx.x;
    int jl = (t & 15) * 4;
#pragma unroll
    for (int s = 0; s < 4; ++s) {
        int kl = s * 16 + (t >> 4);
        if (n0 + jl + 4 <= N) {
            float4 v = *reinterpret_cast<const float4*>(W + (size_t)(k0 + kl) * N + n0 + jl);
            Ts[kl][jl] = f2bf(v.x); Ts[kl][jl + 1] = f2bf(v.y);
            Ts[kl][jl + 2] = f2bf(v.z); Ts[kl][jl + 3] = f2bf(v.w);
        } else {
#pragma unroll
            for (int e = 0; e < 4; ++e)
                Ts[kl][jl + e] = (n0 + jl + e < N) ? f2bf(W[(size_t)(k0 + kl) * N + n0 + jl + e]) : (u16)0;
        }
    }
    __syncthreads();
    int nl = t >> 2, kl0 = (t & 3) * 16;
    u16 tmp[16];
#pragma unroll
    for (int e = 0; e < 16; ++e) tmp[e] = Ts[kl0 + e][nl];
    u16* dst = Wt + (size_t)(n0 + nl) * K + k0 + kl0;
    *reinterpret_cast<uint4*>(dst) = *reinterpret_cast<uint4*>(tmp);
    *reinterpret_cast<uint4*>(dst + 8) = *reinterpret_cast<uint4*>(tmp + 8);
}

// ---------------- K2t: split-K tail GEMM, 128x128 tile, K/SPLITK per block ----------------
// grid = (M/128) * nbt * SPLITK. f32 partials Pf[SPLITK][M][384] (dense stride 384).
// Bt rows ncoff..ncoff+383 (zero-padded past 8480). No store guard: stride-384 buffer.
template <int SPLITK>
__global__ __launch_bounds__(256) void k_tail(const u16* __restrict__ A,
                                              const u16* __restrict__ Bt,
                                              float* __restrict__ Pf,
                                              int M, int ncoff, int lda, int nbt) {
    __shared__ u16 As[8192];
    __shared__ u16 Bs[8192];
    const int Ks = lda / SPLITK;
    int bid = blockIdx.x;
    int nb = bid % nbt;
    int ksl = (bid / nbt) % SPLITK;
    int mb = bid / (nbt * SPLITK);
    int m0 = mb * 128, n0 = nb * 128;
    int koff = ksl * Ks;

    int t = threadIdx.x, lane = t & 63, w = t >> 6;
    int row = t >> 2, kc = (t & 3) * 8;
    int wm = (w >> 1) * 64, wn = (w & 1) * 64;
    int r = lane & 15, q = lane >> 4;

    f32x4 acc[4][4];
#pragma unroll
    for (int a = 0; a < 4; ++a)
#pragma unroll
        for (int b = 0; b < 4; ++b) acc[a][b] = (f32x4){0.f, 0.f, 0.f, 0.f};

    const u16* ga0 = A + (size_t)(m0 + row) * lda + koff + kc;
    const u16* ga1 = A + (size_t)(m0 + 64 + row) * lda + koff + kc;
    const u16* gb0 = Bt + (size_t)(ncoff + n0 + row) * lda + koff + kc;
    const u16* gb1 = Bt + (size_t)(ncoff + n0 + 64 + row) * lda + koff + kc;

    for (int k0 = 0; k0 < Ks; k0 += 64) {
        load_lds16(ga0 + k0,      As + w * 512);
        load_lds16(ga1 + k0,      As + 2048 + w * 512);
        load_lds16(gb0 + k0,      Bs + w * 512);
        load_lds16(gb1 + k0,      Bs + 2048 + w * 512);
        load_lds16(ga0 + k0 + 32, As + 4096 + w * 512);
        load_lds16(ga1 + k0 + 32, As + 4096 + 2048 + w * 512);
        load_lds16(gb0 + k0 + 32, Bs + 4096 + w * 512);
        load_lds16(gb1 + k0 + 32, Bs + 4096 + 2048 + w * 512);
        __syncthreads();
#pragma unroll
        for (int h = 0; h < 2; ++h) {
            bf16x8 af[4], bf[4];
#pragma unroll
            for (int mi = 0; mi < 4; ++mi) af[mi] = ld8(&As[h * 4096 + (wm + mi * 16 + r) * 32 + q * 8]);
#pragma unroll
            for (int ni = 0; ni < 4; ++ni) bf[ni] = ld8(&Bs[h * 4096 + (wn + ni * 16 + r) * 32 + q * 8]);
#pragma unroll
            for (int mi = 0; mi < 4; ++mi)
#pragma unroll
                for (int ni = 0; ni < 4; ++ni)
                    acc[mi][ni] = __builtin_amdgcn_mfma_f32_16x16x32_bf16(af[mi], bf[ni], acc[mi][ni], 0, 0, 0);
        }
        __syncthreads();
    }
#pragma unroll
    for (int mi = 0; mi < 4; ++mi)
#pragma unroll
        for (int ni = 0; ni < 4; ++ni) {
            int lgn = n0 + wn + ni * 16 + r;
#pragma unroll
            for (int rg = 0; rg < 4; ++rg) {
                int gm = m0 + wm + mi * 16 + q * 4 + rg;
                Pf[((size_t)ksl * M + gm) * 384 + lgn] = acc[mi][ni][rg];
            }
        }
}

// ---------------- K2r: reduce 4 tail partials -> proj cols [8192, 8480) bf16 ----------------
__global__ __launch_bounds__(256) void k_tailred(const float* __restrict__ Pf,
                                                 u16* __restrict__ proj) {
    int gid = blockIdx.x * 256 + threadIdx.x;   // 4096 rows * 72 float4 = 294912
    int rowi = gid / 72, c4 = (gid % 72) * 4;
    const float4* P = reinterpret_cast<const float4*>(Pf);
    int idx = rowi * 96 + (c4 >> 2);
    float4 s0 = P[idx], s1 = P[393216 + idx], s2 = P[786432 + idx], s3 = P[1179648 + idx];
    ushort4 o;
    o.x = f2bf(s0.x + s1.x + s2.x + s3.x);
    o.y = f2bf(s0.y + s1.y + s2.y + s3.y);
    o.z = f2bf(s0.z + s1.z + s2.z + s3.z);
    o.w = f2bf(s0.w + s1.w + s2.w + s3.w);
    *reinterpret_cast<ushort4*>(proj + (size_t)rowi * 8480 + 8192 + c4) = o;
}

// ---------------- K2new: 256x256 8-phase GEMM — R2/R5/R7-PROVEN sync structure ----
// 512 thr = 8 waves (2M x 4N); per-wave 128x64 out; BK=64; LDS 128 KiB double-buffered.
// LDS swizzle: 16B-chunk c at row rw holds logical chunk c ^ (rw & 7) (both sides).
// Stage schedule per tile kt (harness-verified R2+R5+R7 at 141 µs; R6 full-tile-ahead
// regressed to 152 — reverted): p0: A1(kt+1) | p2: B0(kt+2)
//   | p3: B1(kt+2), A0(kt+2), barrier, MFMA, vmcnt(6).
// Split-K: ks = swz / tiles; A/B advance ks*Kl cols; f32 partial at Cf + ks*M*Nout.
// lda = row stride of A/Bt (out-proj: lda=4096, Kl=2048). DO NOT EDIT sync (m152).
template <bool F32OUT>
__global__ __launch_bounds__(512, 2) void k_gemm256(const u16* __restrict__ A,
                                                    const u16* __restrict__ Bt,
                                                    u16* __restrict__ Cb,
                                                    float* __restrict__ Cf,
                                                    int M, int Nout, int ldc,
                                                    int lda, int Kl) {
    __shared__ u16 lds[65536];          // A: [2buf][2half][128][64] at 0; B same at 32768
    const int nkt = Kl >> 6;
    int mt = M >> 8;
    int bid = blockIdx.x;
    int swz = (bid & 7) * ((int)gridDim.x >> 3) + (bid >> 3);   // XCD-contiguous (grid%8==0)
    int tiles = mt * (Nout >> 8);
    int tp = swz % tiles, ks = swz / tiles;
    int mb = tp % mt, nb = tp / mt;
    int m0 = mb << 8, n0 = nb << 8;
    int koff = ks * Kl;

    int t = threadIdx.x;
    int ln = t & 63, w = t >> 6;
    int wm = w >> 2, wn = w & 3;
    int r = ln & 15, q = ln >> 4;
    int xq = (q << 3) ^ ((r & 7) << 3);          // swizzled chunk offset within row

    // staging: lane covers row (w*8 + ln/8) of the region; source chunk pre-swizzled
    int rr = ln >> 3;
    int cc8 = ((ln & 7) ^ rr) << 3;
    const u16* Ag = A + (size_t)(m0 + w * 8 + rr) * lda + koff + cc8;
    const u16* Bg = Bt + (size_t)(n0 + w * 8 + rr) * lda + koff + cc8;
    u16* ldsw = lds + (w << 9);
    const size_t R64 = (size_t)lda * 64;     // +64 rows
    const size_t R128 = (size_t)lda * 128;   // +128 rows

    f32x4 acc[8][4];
#pragma unroll
    for (int a = 0; a < 8; ++a)
#pragma unroll
        for (int b = 0; b < 4; ++b) acc[a][b] = (f32x4){0.f, 0.f, 0.f, 0.f};

    auto stageA = [&](int ti, int h) {
        if (ti >= nkt) return;
        const u16* g = Ag + ((size_t)ti << 6) + (h ? R128 : (size_t)0);
        u16* d = ldsw + ((ti & 1) << 14) + (h << 13);
        load_lds16(g, d);
        load_lds16(g + R64, d + 4096);
    };
    auto stageB = [&](int ti, int h) {
        if (ti >= nkt) return;
        const u16* g = Bg + ((size_t)ti << 6) + (h ? R128 : (size_t)0);
        u16* d = ldsw + 32768 + ((ti & 1) << 14) + (h << 13);
        load_lds16(g, d);
        load_lds16(g + R64, d + 4096);
    };

    // prologue: S[0..6] = A0(0) B0(0) B1(0) A1(0) A0(1) B0(1) B1(1); vmcnt(6) lands tile 0.
    stageA(0, 0); stageB(0, 0); stageB(0, 1); stageA(0, 1);
    stageA(1, 0); stageB(1, 0); stageB(1, 1);
    asm volatile("s_waitcnt vmcnt(6)" ::: "memory");
    __builtin_amdgcn_s_barrier();
    asm volatile("" ::: "memory");

    bf16x8 aF[4][2], bLo[2][2], bHi[2][2];

    for (int kt = 0; kt < nkt; ++kt) {
        const u16* Ah = lds + ((kt & 1) << 14) + (wm << 13);
        const u16* Bh = lds + 32768 + ((kt & 1) << 14) + ((wn >> 1) << 13) + ((wn & 1) << 12);

        // ---- phase 0: read A-low (8) + B-low (4); stage A1(kt+1); mfma Mlo x Nlo
#pragma unroll
        for (int mi = 0; mi < 4; ++mi)
#pragma unroll
            for (int ks2 = 0; ks2 < 2; ++ks2)
                aF[mi][ks2] = ld8(Ah + (mi * 16 + r) * 64 + (xq ^ (ks2 << 5)));
#pragma unroll
        for (int ni = 0; ni < 2; ++ni)
#pragma unroll
            for (int ks2 = 0; ks2 < 2; ++ks2)
                bLo[ni][ks2] = ld8(Bh + (ni * 16 + r) * 64 + (xq ^ (ks2 << 5)));
        stageA(kt + 1, 1);
        asm volatile("" ::: "memory");
        __builtin_amdgcn_s_barrier();
        asm volatile("s_waitcnt lgkmcnt(0)" ::: "memory");
        __builtin_amdgcn_s_setprio(1);
#pragma unroll
        for (int mi = 0; mi < 4; ++mi)
#pragma unroll
            for (int ni = 0; ni < 2; ++ni)
#pragma unroll
                for (int ks2 = 0; ks2 < 2; ++ks2)
                    acc[mi][ni] = __builtin_amdgcn_mfma_f32_16x16x32_bf16(aF[mi][ks2], bLo[ni][ks2], acc[mi][ni], 0, 0, 0);
        __builtin_amdgcn_s_setprio(0);
        asm volatile("" ::: "memory");
        __builtin_amdgcn_s_barrier();
        asm volatile("" ::: "memory");

        // ---- phase 1: read B-high (4); no stage; mfma Mlo x Nhi
#pragma unroll
        for (int ni = 0; ni < 2; ++ni)
#pragma unroll
            for (int ks2 = 0; ks2 < 2; ++ks2)
                bHi[ni][ks2] = ld8(Bh + ((ni + 2) * 16 + r) * 64 + (xq ^ (ks2 << 5)));
        asm volatile("" ::: "memory");
        __builtin_amdgcn_s_barrier();
        asm volatile("s_waitcnt lgkmcnt(0)" ::: "memory");
        __builtin_amdgcn_s_setprio(1);
#pragma unroll
        for (int mi = 0; mi < 4; ++mi)
#pragma unroll
            for (int ni = 0; ni < 2; ++ni)
#pragma unroll
                for (int ks2 = 0; ks2 < 2; ++ks2)
                    acc[mi][ni + 2] = __builtin_amdgcn_mfma_f32_16x16x32_bf16(aF[mi][ks2], bHi[ni][ks2], acc[mi][ni + 2], 0, 0, 0);
        __builtin_amdgcn_s_setprio(0);
        asm volatile("" ::: "memory");
        __builtin_amdgcn_s_barrier();
        asm volatile("" ::: "memory");

        // ---- phase 2: read A-high (8); stage B0(kt+2); mfma Mhi x Nhi
#pragma unroll
        for (int mi = 0; mi < 4; ++mi)
#pragma unroll
            for (int ks2 = 0; ks2 < 2; ++ks2)
                aF[mi][ks2] = ld8(Ah + ((mi + 4) * 16 + r) * 64 + (xq ^ (ks2 << 5)));
        stageB(kt + 2, 0);
        asm volatile("" ::: "memory");
        __builtin_amdgcn_s_barrier();
        asm volatile("s_waitcnt lgkmcnt(0)" ::: "memory");
        __builtin_amdgcn_s_setprio(1);
#pragma unroll
        for (int mi = 0; mi < 4; ++mi)
#pragma unroll
            for (int ni = 0; ni < 2; ++ni)
#pragma unroll
                for (int ks2 = 0; ks2 < 2; ++ks2)
                    acc[mi + 4][ni + 2] = __builtin_amdgcn_mfma_f32_16x16x32_bf16(aF[mi][ks2], bHi[ni][ks2], acc[mi + 4][ni + 2], 0, 0, 0);
        __builtin_amdgcn_s_setprio(0);
        asm volatile("" ::: "memory");
        __builtin_amdgcn_s_barrier();
        asm volatile("" ::: "memory");

        // ---- phase 3: no reads; stage B1(kt+2) + A0(kt+2); barrier; mfma Mhi x Nlo; vmcnt(6|0)
        stageB(kt + 2, 1);
        stageA(kt + 2, 0);
        asm volatile("" ::: "memory");
        __builtin_amdgcn_s_barrier();
        __builtin_amdgcn_s_setprio(1);
#pragma unroll
        for (int mi = 0; mi < 4; ++mi)
#pragma unroll
            for (int ni = 0; ni < 2; ++ni)
#pragma unroll
                for (int ks2 = 0; ks2 < 2; ++ks2)
                    acc[mi + 4][ni] = __builtin_amdgcn_mfma_f32_16x16x32_bf16(aF[mi][ks2], bLo[ni][ks2], acc[mi + 4][ni], 0, 0, 0);
        __builtin_amdgcn_s_setprio(0);
        if (kt + 2 < nkt) { asm volatile("s_waitcnt vmcnt(6)" ::: "memory"); }
        else              { asm volatile("s_waitcnt vmcnt(0)" ::: "memory"); }
        __builtin_amdgcn_s_barrier();
        asm volatile("" ::: "memory");
    }

    // epilogue: bf16 store (row stride ldc) or f32 split-K partial (dense Nout)
#pragma unroll
    for (int mi = 0; mi < 8; ++mi)
#pragma unroll
        for (int ni = 0; ni < 4; ++ni) {
            int gn = n0 + wn * 64 + ni * 16 + r;
            if (gn < Nout) {
#pragma unroll
                for (int rg = 0; rg < 4; ++rg) {
                    int gm = m0 + wm * 128 + mi * 16 + q * 4 + rg;
                    if (F32OUT) {
                        Cf[(size_t)ks * M * Nout + (size_t)gm * Nout + gn] = acc[mi][ni][rg];
                    } else {
                        Cb[(size_t)gm * ldc + gn] = f2bf(acc[mi][ni][rg]);
                    }
                }
            }
        }
}

// ---------------- K9: out = x + P0 + P1 (split-K reduce + residual) ----------------
__global__ __launch_bounds__(256) void k_addred(const float* __restrict__ x,
                                                const float* __restrict__ P0,
                                                const float* __restrict__ P1,
                                                float* __restrict__ out) {
    const float4* xv = reinterpret_cast<const float4*>(x);
    const float4* a = reinterpret_cast<const float4*>(P0);
    const float4* b = reinterpret_cast<const float4*>(P1);
    float4* o = reinterpret_cast<float4*>(out);
    for (int k = blockIdx.x * 256 + threadIdx.x; k < 2097152; k += 524288) {
        float4 xx = xv[k], aa = a[k], bb = b[k];
        float4 r;
        r.x = xx.x + aa.x + bb.x; r.y = xx.y + aa.y + bb.y;
        r.z = xx.z + aa.z + bb.z; r.w = xx.w + aa.w + bb.w;
        o[k] = r;
    }
}

// ---------------- K4: dt=softplus, per-chunk inclusive cumsum of A*dt ----------------
__global__ __launch_bounds__(64) void k_dt(const u16* __restrict__ proj,
                                           const float* __restrict__ A_log,
                                           const float* __restrict__ dt_bias,
                                           float* __restrict__ dt,
                                           float* __restrict__ cumla) {
    int bid = blockIdx.x;
    int b = bid >> 10, hh = (bid >> 5) & 31, c = bid & 31;
    int j = threadIdx.x;
    int t = c * 64 + j;
    float z = bf2f(proj[(size_t)(b * 2048 + t) * 8480 + 8192 + hh]) + dt_bias[hh];
    float dtv = (z > 20.f) ? z : log1pf(fexp(z));
    float v = -fexp(A_log[hh]) * dtv;
#pragma unroll
    for (int off = 1; off < 64; off <<= 1) {
        float pv = __shfl_up(v, off, 64);
        if (j >= off) v += pv;
    }
    int base = ((b * 32 + hh) * 32 + c) * 64;
    dt[base + j] = dtv;
    cumla[base + j] = v;
}

// ---------------- K5: intra-chunk, conv+SiLU fused; B/C fragments direct from global ----------------
__global__ __launch_bounds__(256) void k_intra(const u16* __restrict__ proj,
                                               const float* __restrict__ dt,
                                               const float* __restrict__ cumla,
                                               const float* __restrict__ cw,
                                               const float* __restrict__ cb,
                                               const float* __restrict__ Dv,
                                               u16* __restrict__ ybuf,
                                               u16* __restrict__ states) {
    __shared__ u16 Xt[128][72];
    __shared__ u16 Bt[128][72];
    __shared__ union {
        u16 Ms[64][72];                                   // step1 -> step2
        struct { float cwl[4][128]; float cbl[128]; } cv; // staging only
    } sh;
    __shared__ float dts[64], clas[64];
    int bid = blockIdx.x;
    int b = bid >> 10, c = (bid >> 5) & 31, hh = bid & 31;
    int tid = threadIdx.x, lane = tid & 63, w = tid >> 6;
    int r = lane & 15, q = lane >> 4;
    int t0 = b * 2048 + c * 64;
    int sbase = ((b * 32 + hh) * 32 + c) * 64;

    if (tid < 64) { dts[tid] = dt[sbase + tid]; clas[tid] = cumla[sbase + tid]; }
    if (tid < 128) {
        sh.cv.cbl[tid] = cb[hh * 128 + tid];
#pragma unroll
        for (int k = 0; k < 4; ++k) sh.cv.cwl[k][tid] = cw[k * 4096 + hh * 128 + tid];
    }
    __syncthreads();

    // conv(4)+bias+SiLU -> Xt[p][j]; weighted B^T -> Bt[p][j]  (B rows read from global/L2)
    {
        int j = tid & 63;
        float wj = fexp(clas[63] - clas[j]) * dts[j];
        for (int g = tid >> 6; g < 16; g += 4) {
            int p0 = g * 8;
            u16 tb[8];
            *reinterpret_cast<uint4*>(tb) =
                *reinterpret_cast<const uint4*>(proj + (size_t)(t0 + j) * 8480 + 8224 + p0);
            float xv[8];
#pragma unroll
            for (int e = 0; e < 8; ++e) xv[e] = sh.cv.cbl[p0 + e];
#pragma unroll
            for (int kk = 0; kk < 4; ++kk) {
                int tl = c * 64 + j - 3 + kk;
                if (tl >= 0) {
                    u16 srow[8];
                    *reinterpret_cast<uint4*>(srow) =
                        *reinterpret_cast<const uint4*>(proj + (size_t)(b * 2048 + tl) * 8480 + 4096 + hh * 128 + p0);
#pragma unroll
                    for (int e = 0; e < 8; ++e) xv[e] += sh.cv.cwl[kk][p0 + e] * bf2f(srow[e]);
                }
            }
#pragma unroll
            for (int e = 0; e < 8; ++e) {
                float s = xv[e] * frcp(1.f + fexp(-xv[e]));
                Xt[p0 + e][j] = f2bf(s);
                Bt[p0 + e][j] = f2bf(wj * bf2f(tb[e]));
            }
        }
    }
    __syncthreads();

    // step1: M = decay(C·B^T); C and B fragments direct from global (32-head L2 reuse)
    {
        const u16* crow = proj + (size_t)(t0 + w * 16 + r) * 8480 + 8352;
        bf16x8 af[4];
#pragma unroll
        for (int k = 0; k < 4; ++k) af[k] = ld8(crow + k * 32 + q * 8);
#pragma unroll
        for (int tj = 0; tj < 4; ++tj) {
            const u16* brow = proj + (size_t)(t0 + tj * 16 + r) * 8480 + 8224;
            f32x4 acc = (f32x4){0.f, 0.f, 0.f, 0.f};
#pragma unroll
            for (int k = 0; k < 4; ++k)
                acc = __builtin_amdgcn_mfma_f32_16x16x32_bf16(af[k], ld8(brow + k * 32 + q * 8), acc, 0, 0, 0);
            int j = tj * 16 + r;
            float dj = dts[j], cj = clas[j];
#pragma unroll
            for (int rg = 0; rg < 4; ++rg) {
                int i = w * 16 + q * 4 + rg;
                float m = (j <= i) ? acc[rg] * fexp(clas[i] - cj) * dj : 0.f;
                sh.Ms[i][j] = f2bf(m);
            }
        }
    }
    __syncthreads();

    // step2: Y = M @ X + D*X
    {
        bf16x8 af[2];
#pragma unroll
        for (int k = 0; k < 2; ++k) af[k] = ld8(&sh.Ms[w * 16 + r][k * 32 + q * 8]);
#pragma unroll
        for (int tj = 0; tj < 8; ++tj) {
            f32x4 acc = (f32x4){0.f, 0.f, 0.f, 0.f};
#pragma unroll
            for (int k = 0; k < 2; ++k)
                acc = __builtin_amdgcn_mfma_f32_16x16x32_bf16(af[k], ld8(&Xt[tj * 16 + r][k * 32 + q * 8]), acc, 0, 0, 0);
            int p = tj * 16 + r;
            float dv = Dv[hh * 128 + p];
#pragma unroll
            for (int rg = 0; rg < 4; ++rg) {
                int i = w * 16 + q * 4 + rg;
                float v = acc[rg] + dv * bf2f(Xt[p][i]);
                ybuf[(size_t)(t0 + i) * 4096 + hh * 128 + p] = f2bf(v);
            }
        }
    }

    // step3: St[p][n] = sum_j Xt[p][j]*Bt[n][j]
    size_t sb = ((size_t)((b * 32 + hh) * 32 + c)) * 16384;
#pragma unroll
    for (int th = 0; th < 2; ++th) {
        int ti = w + th * 4;
        bf16x8 af[2];
#pragma unroll
        for (int k = 0; k < 2; ++k) af[k] = ld8(&Xt[ti * 16 + r][k * 32 + q * 8]);
#pragma unroll
        for (int tj = 0; tj < 8; ++tj) {
            f32x4 acc = (f32x4){0.f, 0.f, 0.f, 0.f};
#pragma unroll
            for (int k = 0; k < 2; ++k)
                acc = __builtin_amdgcn_mfma_f32_16x16x32_bf16(af[k], ld8(&Bt[tj * 16 + r][k * 32 + q * 8]), acc, 0, 0, 0);
            int n = tj * 16 + r;
#pragma unroll
            for (int rg = 0; rg < 4; ++rg) {
                int p = ti * 16 + q * 4 + rg;
                states[sb + p * 128 + n] = f2bf(acc[rg]);
            }
        }
    }
}

// ---------------- K6: inter-chunk sequential scan, 4 elems/thread (8B vectors) ----------------
__global__ __launch_bounds__(256) void k_scan(u16* __restrict__ states,
                                              const float* __restrict__ cumla) {
    int gid = blockIdx.x * 256 + threadIdx.x;   // 262144 total
    int bh = gid >> 12;
    int q4 = (gid & 4095) * 4;
    size_t base = (size_t)bh * 32 * 16384 + q4;
    float s0 = 0.f, s1 = 0.f, s2 = 0.f, s3 = 0.f;
    for (int c = 0; c < 32; ++c) {
        float cd = fexp(cumla[(bh * 32 + c) * 64 + 63]);
        size_t idx = base + (size_t)c * 16384;
        ushort4 v = *reinterpret_cast<ushort4*>(states + idx);
        float l0 = bf2f(v.x), l1 = bf2f(v.y), l2 = bf2f(v.z), l3 = bf2f(v.w);
        ushort4 o; o.x = f2bf(s0); o.y = f2bf(s1); o.z = f2bf(s2); o.w = f2bf(s3);
        *reinterpret_cast<ushort4*>(states + idx) = o;
        s0 = cd * s0 + l0; s1 = cd * s1 + l1; s2 = cd * s2 + l2; s3 = cd * s3 + l3;
    }
}

// ---------------- K7: Y = ybuf + exp(cla)*C@S, SiLU gate ----------------
__global__ __launch_bounds__(256) void k_inter(const u16* __restrict__ proj,
                                               const u16* __restrict__ states,
                                               const float* __restrict__ cumla,
                                               const u16* __restrict__ ybuf,
                                               u16* __restrict__ ygated) {
    __shared__ u16 Ss[128][136];
    __shared__ float clav[64];
    int bid = blockIdx.x;
    int b = bid >> 10, c = (bid >> 5) & 31, hh = bid & 31;
    int tid = threadIdx.x, lane = tid & 63, w = tid >> 6;
    int r = lane & 15, q = lane >> 4;
    int t0 = b * 2048 + c * 64;
    int sbase = ((b * 32 + hh) * 32 + c) * 64;
    size_t sb = ((size_t)((b * 32 + hh) * 32 + c)) * 16384;

    if (tid < 64) clav[tid] = fexp(cumla[sbase + tid]);
    for (int e = tid; e < 2048; e += 256) {
        int p = e >> 4, n8 = (e & 15) * 8;
        *reinterpret_cast<uint4*>(&Ss[p][n8]) =
            *reinterpret_cast<const uint4*>(states + sb + p * 128 + n8);
    }
    __syncthreads();

    const u16* crow = proj + (size_t)(t0 + w * 16 + r) * 8480 + 8352;
    bf16x8 af[4];
#pragma unroll
    for (int k = 0; k < 4; ++k) af[k] = ld8(crow + k * 32 + q * 8);
#pragma unroll
    for (int tj = 0; tj < 8; ++tj) {
        f32x4 acc = (f32x4){0.f, 0.f, 0.f, 0.f};
#pragma unroll
        for (int k = 0; k < 4; ++k)
            acc = __builtin_amdgcn_mfma_f32_16x16x32_bf16(af[k], ld8(&Ss[tj * 16 + r][k * 32 + q * 8]), acc, 0, 0, 0);
        int p = tj * 16 + r;
        int ch = hh * 128 + p;
#pragma unroll
        for (int rg = 0; rg < 4; ++rg) {
            int i = w * 16 + q * 4 + rg;
            size_t td = (size_t)(t0 + i) * 4096 + ch;
            float v = clav[i] * acc[rg] + bf2f(ybuf[td]);
            float g = bf2f(proj[(size_t)(t0 + i) * 8480 + ch]);
            ygated[td] = f2bf(v * (g * frcp(1.f + fexp(-g))));
        }
    }
}

extern "C" void kernel_launch(void* const* d_in, const int* in_sizes, int n_in,
                              void* d_out, int out_size, void* d_ws, size_t ws_size,
                              hipStream_t stream) {
    const float* x          = (const float*)d_in[0];
    const float* norm_scale = (const float*)d_in[1];
    const float* in_proj_w  = (const float*)d_in[2];
    const float* conv_w     = (const float*)d_in[3];
    const float* conv_b     = (const float*)d_in[4];
    const float* A_log      = (const float*)d_in[5];
    const float* dt_bias    = (const float*)d_in[6];
    const float* Dv         = (const float*)d_in[7];
    const float* out_w      = (const float*)d_in[8];
    float* out = (float*)d_out;

    char* ws = (char*)d_ws;
    u16*   states = (u16*)(ws);               // [0,67.1M); h aliases [0,16.8M), wbt [16.8M,52.5M)
    u16*   h      = (u16*)(ws);
    u16*   wbt    = (u16*)(ws + 16777216);    // 8704x2048 bf16 (rows 8480..8703 zero)
    float* parts  = (float*)(ws);             // out-proj split-K partials 2x 4096x2048 f32 (after k_inter)
    u16*   proj   = (u16*)(ws + 67108864);    // 69,468,160
    u16*   owt    = (u16*)(ws + 136577024);   // 2048x4096 bf16
    u16*   ybuf   = (u16*)(ws + 170131456);   // 33,554,432 (also ygated)
    float* tailP  = (float*)(ws + 170131456); // tail partials 4x 4096x384 f32 = 25.2M (pre-intra)
    float* dt     = (float*)(ws + 203685888);
    float* cumla  = (float*)(ws + 204210176);

    k_rmsnorm<<<4096, 256, 0, stream>>>(x, norm_scale, h);
    k_wcast<<<dim3(136, 32), 256, 0, stream>>>(in_proj_w, wbt, 2048, 8480);
    // proj tail: cols 8192..8480, split-K=4: 32 mb x 3 nb x 4 ks = 384 blocks, K=512 each
    k_tail<4><<<384, 256, 0, stream>>>(h, wbt, tailP, 4096, 8192, 2048, 3);
    k_tailred<<<1152, 256, 0, stream>>>(tailP, proj);
    // proj main: cols 0..8192, 512 blocks of 256x256 = exactly 2 rounds; ldc=8480
    k_gemm256<false><<<512, 512, 0, stream>>>(h, wbt, proj, nullptr,
                                              4096, 8192, 8480, 2048, 2048);
    k_dt<<<2048, 64, 0, stream>>>(proj, A_log, dt_bias, dt, cumla);
    k_intra<<<2048, 256, 0, stream>>>(proj, dt, cumla, conv_w, conv_b, Dv, ybuf, states);
    k_scan<<<1024, 256, 0, stream>>>(states, cumla);
    k_inter<<<2048, 256, 0, stream>>>(proj, states, cumla, ybuf, ybuf);
    k_wcast<<<dim3(32, 64), 256, 0, stream>>>(out_w, owt, 4096, 2048);
    // out-proj: split-K=2, 128 tiles x 2 = 256 blocks = 1 round; f32 partials into parts
    k_gemm256<true><<<256, 512, 0, stream>>>(ybuf, owt, nullptr, parts,
                                             4096, 2048, 2048, 4096, 2048);
    k_addred<<<2048, 256, 0, stream>>>(x, parts, parts + 8388608, out);
}

// Round 10
// 512.451 us; speedup vs baseline: 1.1579x; 1.0251x over previous
//
#include <hip/hip_runtime.h>

typedef unsigned short u16;
typedef unsigned short u16x8 __attribute__((ext_vector_type(8)));
typedef __bf16 bf16x8 __attribute__((ext_vector_type(8)));
typedef float f32x4 __attribute__((ext_vector_type(4)));

// B=2, T=2048, N_EMBD=2048, D_INNER=4096, N_HEADS=32, HEAD_DIM=128, D_STATE=128,
// PROJ=8480 (= 8192 main + 288 tail), CHUNK=64, n_chunks=32. External fp32; staging bf16.
// proj row: [0,4096) gate | [4096,8192) ssm_in | [8192,8224) dt | [8224,8352) B | [8352,8480) C
// NOTE (R9 lesson): cross-run clock noise is ±10-14% (R7 main=141µs@1544GB/s vs R9 160µs@1359);
// only within-run dispatch comparisons are reliable.

__device__ __forceinline__ float bf2f(u16 u) {
    union { unsigned int i; float f; } v; v.i = ((unsigned int)u) << 16; return v.f;
}
__device__ __forceinline__ u16 f2bf(float f) {
    unsigned int u = __float_as_uint(f);
    u += 0x7fffu + ((u >> 16) & 1u);   // RNE
    return (u16)(u >> 16);
}
__device__ __forceinline__ bf16x8 ld8(const u16* p) {
    return __builtin_bit_cast(bf16x8, *reinterpret_cast<const u16x8*>(p));
}
__device__ __forceinline__ void load_lds16(const u16* g, u16* l) {
    __builtin_amdgcn_global_load_lds(
        (const __attribute__((address_space(1))) unsigned int*)g,
        (__attribute__((address_space(3))) unsigned int*)l, 16, 0, 0);
}
__device__ __forceinline__ float fexp(float x) { return __expf(x); }
__device__ __forceinline__ float frcp(float x) { return __builtin_amdgcn_rcpf(x); }

// ---------------- shared wcast body: fp32 [K][N] -> bf16 [Npad][K], one 64x64 tile ----------------
__device__ __forceinline__ void wcast_tile(const float* __restrict__ W, u16* __restrict__ Wt,
                                           int K, int N, int n0, int k0, int t,
                                           u16 (*Ts)[72]) {
    int jl = (t & 15) * 4;
#pragma unroll
    for (int s = 0; s < 4; ++s) {
        int kl = s * 16 + (t >> 4);
        if (n0 + jl + 4 <= N) {
            float4 v = *reinterpret_cast<const float4*>(W + (size_t)(k0 + kl) * N + n0 + jl);
            Ts[kl][jl] = f2bf(v.x); Ts[kl][jl + 1] = f2bf(v.y);
            Ts[kl][jl + 2] = f2bf(v.z); Ts[kl][jl + 3] = f2bf(v.w);
        } else {
#pragma unroll
            for (int e = 0; e < 4; ++e)
                Ts[kl][jl + e] = (n0 + jl + e < N) ? f2bf(W[(size_t)(k0 + kl) * N + n0 + jl + e]) : (u16)0;
        }
    }
    __syncthreads();
    int nl = t >> 2, kl0 = (t & 3) * 16;
    u16 tmp[16];
#pragma unroll
    for (int e = 0; e < 16; ++e) tmp[e] = Ts[kl0 + e][nl];
    u16* dst = Wt + (size_t)(n0 + nl) * K + k0 + kl0;
    *reinterpret_cast<uint4*>(dst) = *reinterpret_cast<uint4*>(tmp);
    *reinterpret_cast<uint4*>(dst + 8) = *reinterpret_cast<uint4*>(tmp + 8);
}

// ---------------- K_pre: rmsnorm (blocks 0..4095) ∥ wcast in_proj (blocks 4096..8447) ----------------
__global__ __launch_bounds__(256) void k_pre(const float* __restrict__ x,
                                             const float* __restrict__ scale,
                                             u16* __restrict__ h,
                                             const float* __restrict__ W,
                                             u16* __restrict__ Wt) {
    __shared__ __align__(16) char smem[9216];
    int bid = blockIdx.x, tid = threadIdx.x;
    if (bid < 4096) {
        // RMSNorm row
        float* red = reinterpret_cast<float*>(smem);
        const float4* xr = reinterpret_cast<const float4*>(x + (size_t)bid * 2048);
        float4 v0 = xr[tid], v1 = xr[tid + 256];
        float ss = v0.x*v0.x + v0.y*v0.y + v0.z*v0.z + v0.w*v0.w
                 + v1.x*v1.x + v1.y*v1.y + v1.z*v1.z + v1.w*v1.w;
#pragma unroll
        for (int off = 32; off > 0; off >>= 1) ss += __shfl_down(ss, off, 64);
        if ((tid & 63) == 0) red[tid >> 6] = ss;
        __syncthreads();
        float r = rsqrtf((red[0] + red[1] + red[2] + red[3]) * (1.f / 2048.f) + 1e-6f);
        const float4* sc = reinterpret_cast<const float4*>(scale);
        float4 s0 = sc[tid], s1 = sc[tid + 256];
        ushort4 o0, o1;
        o0.x = f2bf(v0.x * r * s0.x); o0.y = f2bf(v0.y * r * s0.y);
        o0.z = f2bf(v0.z * r * s0.z); o0.w = f2bf(v0.w * r * s0.w);
        o1.x = f2bf(v1.x * r * s1.x); o1.y = f2bf(v1.y * r * s1.y);
        o1.z = f2bf(v1.z * r * s1.z); o1.w = f2bf(v1.w * r * s1.w);
        ushort4* hr = reinterpret_cast<ushort4*>(h + (size_t)bid * 2048);
        hr[tid] = o0; hr[tid + 256] = o1;
    } else {
        int wb = bid - 4096;                       // 4352 = 136 n-tiles x 32 k-tiles
        int n0 = (wb % 136) * 64, k0 = (wb / 136) * 64;
        wcast_tile(W, Wt, 2048, 8480, n0, k0, tid, reinterpret_cast<u16(*)[72]>(smem));
    }
}

// ---------------- K_mid: split-K tail GEMM (blocks 0..383) ∥ wcast out_proj (384..2431) ------------
// tail: f32 partials Pf[4][M][384] (dense stride 384); Bt rows 8192..8575 zero-padded past 8480.
__global__ __launch_bounds__(256) void k_mid(const u16* __restrict__ A,
                                             const u16* __restrict__ Bt,
                                             float* __restrict__ Pf,
                                             const float* __restrict__ W,
                                             u16* __restrict__ Wt) {
    __shared__ __align__(16) u16 smem[16384];      // tail: As | Bs ; wcast: Ts[64][72]
    int bid = blockIdx.x, t = threadIdx.x;
    if (bid >= 384) {
        int wb = bid - 384;                        // 2048 = 32 n-tiles x 64 k-tiles
        int n0 = (wb % 32) * 64, k0 = (wb / 32) * 64;
        wcast_tile(W, Wt, 4096, 2048, n0, k0, t, reinterpret_cast<u16(*)[72]>(smem));
        return;
    }
    u16* As = smem;
    u16* Bs = smem + 8192;
    const int lda = 2048, Ks = 512, M = 4096, ncoff = 8192;
    int nb = bid % 3;
    int ksl = (bid / 3) & 3;
    int mb = bid / 12;
    int m0 = mb * 128, n0 = nb * 128;
    int koff = ksl * Ks;

    int lane = t & 63, w = t >> 6;
    int row = t >> 2, kc = (t & 3) * 8;
    int wm = (w >> 1) * 64, wn = (w & 1) * 64;
    int r = lane & 15, q = lane >> 4;

    f32x4 acc[4][4];
#pragma unroll
    for (int a = 0; a < 4; ++a)
#pragma unroll
        for (int b = 0; b < 4; ++b) acc[a][b] = (f32x4){0.f, 0.f, 0.f, 0.f};

    const u16* ga0 = A + (size_t)(m0 + row) * lda + koff + kc;
    const u16* ga1 = A + (size_t)(m0 + 64 + row) * lda + koff + kc;
    const u16* gb0 = Bt + (size_t)(ncoff + n0 + row) * lda + koff + kc;
    const u16* gb1 = Bt + (size_t)(ncoff + n0 + 64 + row) * lda + koff + kc;

    for (int k0 = 0; k0 < Ks; k0 += 64) {
        load_lds16(ga0 + k0,      As + w * 512);
        load_lds16(ga1 + k0,      As + 2048 + w * 512);
        load_lds16(gb0 + k0,      Bs + w * 512);
        load_lds16(gb1 + k0,      Bs + 2048 + w * 512);
        load_lds16(ga0 + k0 + 32, As + 4096 + w * 512);
        load_lds16(ga1 + k0 + 32, As + 4096 + 2048 + w * 512);
        load_lds16(gb0 + k0 + 32, Bs + 4096 + w * 512);
        load_lds16(gb1 + k0 + 32, Bs + 4096 + 2048 + w * 512);
        __syncthreads();
#pragma unroll
        for (int hh = 0; hh < 2; ++hh) {
            bf16x8 af[4], bf[4];
#pragma unroll
            for (int mi = 0; mi < 4; ++mi) af[mi] = ld8(&As[hh * 4096 + (wm + mi * 16 + r) * 32 + q * 8]);
#pragma unroll
            for (int ni = 0; ni < 4; ++ni) bf[ni] = ld8(&Bs[hh * 4096 + (wn + ni * 16 + r) * 32 + q * 8]);
#pragma unroll
            for (int mi = 0; mi < 4; ++mi)
#pragma unroll
                for (int ni = 0; ni < 4; ++ni)
                    acc[mi][ni] = __builtin_amdgcn_mfma_f32_16x16x32_bf16(af[mi], bf[ni], acc[mi][ni], 0, 0, 0);
        }
        __syncthreads();
    }
#pragma unroll
    for (int mi = 0; mi < 4; ++mi)
#pragma unroll
        for (int ni = 0; ni < 4; ++ni) {
            int lgn = n0 + wn + ni * 16 + r;
#pragma unroll
            for (int rg = 0; rg < 4; ++rg) {
                int gm = m0 + wm + mi * 16 + q * 4 + rg;
                Pf[((size_t)ksl * M + gm) * 384 + lgn] = acc[mi][ni][rg];
            }
        }
}

// ---------------- K2r: reduce 4 tail partials -> proj cols [8192, 8480) bf16 ----------------
__global__ __launch_bounds__(256) void k_tailred(const float* __restrict__ Pf,
                                                 u16* __restrict__ proj) {
    int gid = blockIdx.x * 256 + threadIdx.x;   // 4096 rows * 72 float4 = 294912
    int rowi = gid / 72, c4 = (gid % 72) * 4;
    const float4* P = reinterpret_cast<const float4*>(Pf);
    int idx = rowi * 96 + (c4 >> 2);
    float4 s0 = P[idx], s1 = P[393216 + idx], s2 = P[786432 + idx], s3 = P[1179648 + idx];
    ushort4 o;
    o.x = f2bf(s0.x + s1.x + s2.x + s3.x);
    o.y = f2bf(s0.y + s1.y + s2.y + s3.y);
    o.z = f2bf(s0.z + s1.z + s2.z + s3.z);
    o.w = f2bf(s0.w + s1.w + s2.w + s3.w);
    *reinterpret_cast<ushort4*>(proj + (size_t)rowi * 8480 + 8192 + c4) = o;
}

// ---------------- K2new: 256x256 8-phase GEMM — R2/R5/R7-PROVEN sync structure ----
// 512 thr = 8 waves (2M x 4N); per-wave 128x64 out; BK=64; LDS 128 KiB double-buffered.
// LDS swizzle: 16B-chunk c at row rw holds logical chunk c ^ (rw & 7) (both sides).
// Stage schedule per tile kt (harness-verified R2+R5+R7; R6 full-tile-ahead regressed,
// reverted): p0: A1(kt+1) | p2: B0(kt+2) | p3: B1(kt+2), A0(kt+2), barrier, MFMA, vmcnt(6).
// Split-K: ks = swz / tiles; A/B advance ks*Kl cols; f32 partial at Cf + ks*M*Nout.
// lda = row stride of A/Bt (out-proj: lda=4096, Kl=2048). DO NOT EDIT sync (m152).
template <bool F32OUT>
__global__ __launch_bounds__(512, 2) void k_gemm256(const u16* __restrict__ A,
                                                    const u16* __restrict__ Bt,
                                                    u16* __restrict__ Cb,
                                                    float* __restrict__ Cf,
                                                    int M, int Nout, int ldc,
                                                    int lda, int Kl) {
    __shared__ u16 lds[65536];          // A: [2buf][2half][128][64] at 0; B same at 32768
    const int nkt = Kl >> 6;
    int mt = M >> 8;
    int bid = blockIdx.x;
    int swz = (bid & 7) * ((int)gridDim.x >> 3) + (bid >> 3);   // XCD-contiguous (grid%8==0)
    int tiles = mt * (Nout >> 8);
    int tp = swz % tiles, ks = swz / tiles;
    int mb = tp % mt, nb = tp / mt;
    int m0 = mb << 8, n0 = nb << 8;
    int koff = ks * Kl;

    int t = threadIdx.x;
    int ln = t & 63, w = t >> 6;
    int wm = w >> 2, wn = w & 3;
    int r = ln & 15, q = ln >> 4;
    int xq = (q << 3) ^ ((r & 7) << 3);          // swizzled chunk offset within row

    // staging: lane covers row (w*8 + ln/8) of the region; source chunk pre-swizzled
    int rr = ln >> 3;
    int cc8 = ((ln & 7) ^ rr) << 3;
    const u16* Ag = A + (size_t)(m0 + w * 8 + rr) * lda + koff + cc8;
    const u16* Bg = Bt + (size_t)(n0 + w * 8 + rr) * lda + koff + cc8;
    u16* ldsw = lds + (w << 9);
    const size_t R64 = (size_t)lda * 64;     // +64 rows
    const size_t R128 = (size_t)lda * 128;   // +128 rows

    f32x4 acc[8][4];
#pragma unroll
    for (int a = 0; a < 8; ++a)
#pragma unroll
        for (int b = 0; b < 4; ++b) acc[a][b] = (f32x4){0.f, 0.f, 0.f, 0.f};

    auto stageA = [&](int ti, int h) {
        if (ti >= nkt) return;
        const u16* g = Ag + ((size_t)ti << 6) + (h ? R128 : (size_t)0);
        u16* d = ldsw + ((ti & 1) << 14) + (h << 13);
        load_lds16(g, d);
        load_lds16(g + R64, d + 4096);
    };
    auto stageB = [&](int ti, int h) {
        if (ti >= nkt) return;
        const u16* g = Bg + ((size_t)ti << 6) + (h ? R128 : (size_t)0);
        u16* d = ldsw + 32768 + ((ti & 1) << 14) + (h << 13);
        load_lds16(g, d);
        load_lds16(g + R64, d + 4096);
    };

    // prologue: S[0..6] = A0(0) B0(0) B1(0) A1(0) A0(1) B0(1) B1(1); vmcnt(6) lands tile 0.
    stageA(0, 0); stageB(0, 0); stageB(0, 1); stageA(0, 1);
    stageA(1, 0); stageB(1, 0); stageB(1, 1);
    asm volatile("s_waitcnt vmcnt(6)" ::: "memory");
    __builtin_amdgcn_s_barrier();
    asm volatile("" ::: "memory");

    bf16x8 aF[4][2], bLo[2][2], bHi[2][2];

    for (int kt = 0; kt < nkt; ++kt) {
        const u16* Ah = lds + ((kt & 1) << 14) + (wm << 13);
        const u16* Bh = lds + 32768 + ((kt & 1) << 14) + ((wn >> 1) << 13) + ((wn & 1) << 12);

        // ---- phase 0: read A-low (8) + B-low (4); stage A1(kt+1); mfma Mlo x Nlo
#pragma unroll
        for (int mi = 0; mi < 4; ++mi)
#pragma unroll
            for (int ks2 = 0; ks2 < 2; ++ks2)
                aF[mi][ks2] = ld8(Ah + (mi * 16 + r) * 64 + (xq ^ (ks2 << 5)));
#pragma unroll
        for (int ni = 0; ni < 2; ++ni)
#pragma unroll
            for (int ks2 = 0; ks2 < 2; ++ks2)
                bLo[ni][ks2] = ld8(Bh + (ni * 16 + r) * 64 + (xq ^ (ks2 << 5)));
        stageA(kt + 1, 1);
        asm volatile("" ::: "memory");
        __builtin_amdgcn_s_barrier();
        asm volatile("s_waitcnt lgkmcnt(0)" ::: "memory");
        __builtin_amdgcn_s_setprio(1);
#pragma unroll
        for (int mi = 0; mi < 4; ++mi)
#pragma unroll
            for (int ni = 0; ni < 2; ++ni)
#pragma unroll
                for (int ks2 = 0; ks2 < 2; ++ks2)
                    acc[mi][ni] = __builtin_amdgcn_mfma_f32_16x16x32_bf16(aF[mi][ks2], bLo[ni][ks2], acc[mi][ni], 0, 0, 0);
        __builtin_amdgcn_s_setprio(0);
        asm volatile("" ::: "memory");
        __builtin_amdgcn_s_barrier();
        asm volatile("" ::: "memory");

        // ---- phase 1: read B-high (4); no stage; mfma Mlo x Nhi
#pragma unroll
        for (int ni = 0; ni < 2; ++ni)
#pragma unroll
            for (int ks2 = 0; ks2 < 2; ++ks2)
                bHi[ni][ks2] = ld8(Bh + ((ni + 2) * 16 + r) * 64 + (xq ^ (ks2 << 5)));
        asm volatile("" ::: "memory");
        __builtin_amdgcn_s_barrier();
        asm volatile("s_waitcnt lgkmcnt(0)" ::: "memory");
        __builtin_amdgcn_s_setprio(1);
#pragma unroll
        for (int mi = 0; mi < 4; ++mi)
#pragma unroll
            for (int ni = 0; ni < 2; ++ni)
#pragma unroll
                for (int ks2 = 0; ks2 < 2; ++ks2)
                    acc[mi][ni + 2] = __builtin_amdgcn_mfma_f32_16x16x32_bf16(aF[mi][ks2], bHi[ni][ks2], acc[mi][ni + 2], 0, 0, 0);
        __builtin_amdgcn_s_setprio(0);
        asm volatile("" ::: "memory");
        __builtin_amdgcn_s_barrier();
        asm volatile("" ::: "memory");

        // ---- phase 2: read A-high (8); stage B0(kt+2); mfma Mhi x Nhi
#pragma unroll
        for (int mi = 0; mi < 4; ++mi)
#pragma unroll
            for (int ks2 = 0; ks2 < 2; ++ks2)
                aF[mi][ks2] = ld8(Ah + ((mi + 4) * 16 + r) * 64 + (xq ^ (ks2 << 5)));
        stageB(kt + 2, 0);
        asm volatile("" ::: "memory");
        __builtin_amdgcn_s_barrier();
        asm volatile("s_waitcnt lgkmcnt(0)" ::: "memory");
        __builtin_amdgcn_s_setprio(1);
#pragma unroll
        for (int mi = 0; mi < 4; ++mi)
#pragma unroll
            for (int ni = 0; ni < 2; ++ni)
#pragma unroll
                for (int ks2 = 0; ks2 < 2; ++ks2)
                    acc[mi + 4][ni + 2] = __builtin_amdgcn_mfma_f32_16x16x32_bf16(aF[mi][ks2], bHi[ni][ks2], acc[mi + 4][ni + 2], 0, 0, 0);
        __builtin_amdgcn_s_setprio(0);
        asm volatile("" ::: "memory");
        __builtin_amdgcn_s_barrier();
        asm volatile("" ::: "memory");

        // ---- phase 3: no reads; stage B1(kt+2) + A0(kt+2); barrier; mfma Mhi x Nlo; vmcnt(6|0)
        stageB(kt + 2, 1);
        stageA(kt + 2, 0);
        asm volatile("" ::: "memory");
        __builtin_amdgcn_s_barrier();
        __builtin_amdgcn_s_setprio(1);
#pragma unroll
        for (int mi = 0; mi < 4; ++mi)
#pragma unroll
            for (int ni = 0; ni < 2; ++ni)
#pragma unroll
                for (int ks2 = 0; ks2 < 2; ++ks2)
                    acc[mi + 4][ni] = __builtin_amdgcn_mfma_f32_16x16x32_bf16(aF[mi][ks2], bLo[ni][ks2], acc[mi + 4][ni], 0, 0, 0);
        __builtin_amdgcn_s_setprio(0);
        if (kt + 2 < nkt) { asm volatile("s_waitcnt vmcnt(6)" ::: "memory"); }
        else              { asm volatile("s_waitcnt vmcnt(0)" ::: "memory"); }
        __builtin_amdgcn_s_barrier();
        asm volatile("" ::: "memory");
    }

    // epilogue: bf16 store (row stride ldc) or f32 split-K partial (dense Nout)
#pragma unroll
    for (int mi = 0; mi < 8; ++mi)
#pragma unroll
        for (int ni = 0; ni < 4; ++ni) {
            int gn = n0 + wn * 64 + ni * 16 + r;
            if (gn < Nout) {
#pragma unroll
                for (int rg = 0; rg < 4; ++rg) {
                    int gm = m0 + wm * 128 + mi * 16 + q * 4 + rg;
                    if (F32OUT) {
                        Cf[(size_t)ks * M * Nout + (size_t)gm * Nout + gn] = acc[mi][ni][rg];
                    } else {
                        Cb[(size_t)gm * ldc + gn] = f2bf(acc[mi][ni][rg]);
                    }
                }
            }
        }
}

// ---------------- K9: out = x + P0 + P1 (split-K reduce + residual) ----------------
__global__ __launch_bounds__(256) void k_addred(const float* __restrict__ x,
                                                const float* __restrict__ P0,
                                                const float* __restrict__ P1,
                                                float* __restrict__ out) {
    const float4* xv = reinterpret_cast<const float4*>(x);
    const float4* a = reinterpret_cast<const float4*>(P0);
    const float4* b = reinterpret_cast<const float4*>(P1);
    float4* o = reinterpret_cast<float4*>(out);
    for (int k = blockIdx.x * 256 + threadIdx.x; k < 2097152; k += 524288) {
        float4 xx = xv[k], aa = a[k], bb = b[k];
        float4 r;
        r.x = xx.x + aa.x + bb.x; r.y = xx.y + aa.y + bb.y;
        r.z = xx.z + aa.z + bb.z; r.w = xx.w + aa.w + bb.w;
        o[k] = r;
    }
}

// ---------------- K4: dt=softplus, per-chunk inclusive cumsum of A*dt ----------------
__global__ __launch_bounds__(64) void k_dt(const u16* __restrict__ proj,
                                           const float* __restrict__ A_log,
                                           const float* __restrict__ dt_bias,
                                           float* __restrict__ dt,
                                           float* __restrict__ cumla) {
    int bid = blockIdx.x;
    int b = bid >> 10, hh = (bid >> 5) & 31, c = bid & 31;
    int j = threadIdx.x;
    int t = c * 64 + j;
    float z = bf2f(proj[(size_t)(b * 2048 + t) * 8480 + 8192 + hh]) + dt_bias[hh];
    float dtv = (z > 20.f) ? z : log1pf(fexp(z));
    float v = -fexp(A_log[hh]) * dtv;
#pragma unroll
    for (int off = 1; off < 64; off <<= 1) {
        float pv = __shfl_up(v, off, 64);
        if (j >= off) v += pv;
    }
    int base = ((b * 32 + hh) * 32 + c) * 64;
    dt[base + j] = dtv;
    cumla[base + j] = v;
}

// ---------------- K5: intra-chunk, conv+SiLU fused; B/C fragments direct from global ----------------
__global__ __launch_bounds__(256) void k_intra(const u16* __restrict__ proj,
                                               const float* __restrict__ dt,
                                               const float* __restrict__ cumla,
                                               const float* __restrict__ cw,
                                               const float* __restrict__ cb,
                                               const float* __restrict__ Dv,
                                               u16* __restrict__ ybuf,
                                               u16* __restrict__ states) {
    __shared__ u16 Xt[128][72];
    __shared__ u16 Bt[128][72];
    __shared__ union {
        u16 Ms[64][72];                                   // step1 -> step2
        struct { float cwl[4][128]; float cbl[128]; } cv; // staging only
    } sh;
    __shared__ float dts[64], clas[64];
    int bid = blockIdx.x;
    int b = bid >> 10, c = (bid >> 5) & 31, hh = bid & 31;
    int tid = threadIdx.x, lane = tid & 63, w = tid >> 6;
    int r = lane & 15, q = lane >> 4;
    int t0 = b * 2048 + c * 64;
    int sbase = ((b * 32 + hh) * 32 + c) * 64;

    if (tid < 64) { dts[tid] = dt[sbase + tid]; clas[tid] = cumla[sbase + tid]; }
    if (tid < 128) {
        sh.cv.cbl[tid] = cb[hh * 128 + tid];
#pragma unroll
        for (int k = 0; k < 4; ++k) sh.cv.cwl[k][tid] = cw[k * 4096 + hh * 128 + tid];
    }
    __syncthreads();

    // conv(4)+bias+SiLU -> Xt[p][j]; weighted B^T -> Bt[p][j]  (B rows read from global/L2)
    {
        int j = tid & 63;
        float wj = fexp(clas[63] - clas[j]) * dts[j];
        for (int g = tid >> 6; g < 16; g += 4) {
            int p0 = g * 8;
            u16 tb[8];
            *reinterpret_cast<uint4*>(tb) =
                *reinterpret_cast<const uint4*>(proj + (size_t)(t0 + j) * 8480 + 8224 + p0);
            float xv[8];
#pragma unroll
            for (int e = 0; e < 8; ++e) xv[e] = sh.cv.cbl[p0 + e];
#pragma unroll
            for (int kk = 0; kk < 4; ++kk) {
                int tl = c * 64 + j - 3 + kk;
                if (tl >= 0) {
                    u16 srow[8];
                    *reinterpret_cast<uint4*>(srow) =
                        *reinterpret_cast<const uint4*>(proj + (size_t)(b * 2048 + tl) * 8480 + 4096 + hh * 128 + p0);
#pragma unroll
                    for (int e = 0; e < 8; ++e) xv[e] += sh.cv.cwl[kk][p0 + e] * bf2f(srow[e]);
                }
            }
#pragma unroll
            for (int e = 0; e < 8; ++e) {
                float s = xv[e] * frcp(1.f + fexp(-xv[e]));
                Xt[p0 + e][j] = f2bf(s);
                Bt[p0 + e][j] = f2bf(wj * bf2f(tb[e]));
            }
        }
    }
    __syncthreads();

    // step1: M = decay(C·B^T); C and B fragments direct from global (32-head L2 reuse)
    {
        const u16* crow = proj + (size_t)(t0 + w * 16 + r) * 8480 + 8352;
        bf16x8 af[4];
#pragma unroll
        for (int k = 0; k < 4; ++k) af[k] = ld8(crow + k * 32 + q * 8);
#pragma unroll
        for (int tj = 0; tj < 4; ++tj) {
            const u16* brow = proj + (size_t)(t0 + tj * 16 + r) * 8480 + 8224;
            f32x4 acc = (f32x4){0.f, 0.f, 0.f, 0.f};
#pragma unroll
            for (int k = 0; k < 4; ++k)
                acc = __builtin_amdgcn_mfma_f32_16x16x32_bf16(af[k], ld8(brow + k * 32 + q * 8), acc, 0, 0, 0);
            int j = tj * 16 + r;
            float dj = dts[j], cj = clas[j];
#pragma unroll
            for (int rg = 0; rg < 4; ++rg) {
                int i = w * 16 + q * 4 + rg;
                float m = (j <= i) ? acc[rg] * fexp(clas[i] - cj) * dj : 0.f;
                sh.Ms[i][j] = f2bf(m);
            }
        }
    }
    __syncthreads();

    // step2: Y = M @ X + D*X
    {
        bf16x8 af[2];
#pragma unroll
        for (int k = 0; k < 2; ++k) af[k] = ld8(&sh.Ms[w * 16 + r][k * 32 + q * 8]);
#pragma unroll
        for (int tj = 0; tj < 8; ++tj) {
            f32x4 acc = (f32x4){0.f, 0.f, 0.f, 0.f};
#pragma unroll
            for (int k = 0; k < 2; ++k)
                acc = __builtin_amdgcn_mfma_f32_16x16x32_bf16(af[k], ld8(&Xt[tj * 16 + r][k * 32 + q * 8]), acc, 0, 0, 0);
            int p = tj * 16 + r;
            float dv = Dv[hh * 128 + p];
#pragma unroll
            for (int rg = 0; rg < 4; ++rg) {
                int i = w * 16 + q * 4 + rg;
                float v = acc[rg] + dv * bf2f(Xt[p][i]);
                ybuf[(size_t)(t0 + i) * 4096 + hh * 128 + p] = f2bf(v);
            }
        }
    }

    // step3: St[p][n] = sum_j Xt[p][j]*Bt[n][j]
    size_t sb = ((size_t)((b * 32 + hh) * 32 + c)) * 16384;
#pragma unroll
    for (int th = 0; th < 2; ++th) {
        int ti = w + th * 4;
        bf16x8 af[2];
#pragma unroll
        for (int k = 0; k < 2; ++k) af[k] = ld8(&Xt[ti * 16 + r][k * 32 + q * 8]);
#pragma unroll
        for (int tj = 0; tj < 8; ++tj) {
            f32x4 acc = (f32x4){0.f, 0.f, 0.f, 0.f};
#pragma unroll
            for (int k = 0; k < 2; ++k)
                acc = __builtin_amdgcn_mfma_f32_16x16x32_bf16(af[k], ld8(&Bt[tj * 16 + r][k * 32 + q * 8]), acc, 0, 0, 0);
            int n = tj * 16 + r;
#pragma unroll
            for (int rg = 0; rg < 4; ++rg) {
                int p = ti * 16 + q * 4 + rg;
                states[sb + p * 128 + n] = f2bf(acc[rg]);
            }
        }
    }
}

// ---------------- K6: inter-chunk sequential scan, 4 elems/thread (8B vectors) ----------------
__global__ __launch_bounds__(256) void k_scan(u16* __restrict__ states,
                                              const float* __restrict__ cumla) {
    int gid = blockIdx.x * 256 + threadIdx.x;   // 262144 total
    int bh = gid >> 12;
    int q4 = (gid & 4095) * 4;
    size_t base = (size_t)bh * 32 * 16384 + q4;
    float s0 = 0.f, s1 = 0.f, s2 = 0.f, s3 = 0.f;
    for (int c = 0; c < 32; ++c) {
        float cd = fexp(cumla[(bh * 32 + c) * 64 + 63]);
        size_t idx = base + (size_t)c * 16384;
        ushort4 v = *reinterpret_cast<ushort4*>(states + idx);
        float l0 = bf2f(v.x), l1 = bf2f(v.y), l2 = bf2f(v.z), l3 = bf2f(v.w);
        ushort4 o; o.x = f2bf(s0); o.y = f2bf(s1); o.z = f2bf(s2); o.w = f2bf(s3);
        *reinterpret_cast<ushort4*>(states + idx) = o;
        s0 = cd * s0 + l0; s1 = cd * s1 + l1; s2 = cd * s2 + l2; s3 = cd * s3 + l3;
    }
}

// ---------------- K7: Y = ybuf + exp(cla)*C@S, SiLU gate ----------------
__global__ __launch_bounds__(256) void k_inter(const u16* __restrict__ proj,
                                               const u16* __restrict__ states,
                                               const float* __restrict__ cumla,
                                               const u16* __restrict__ ybuf,
                                               u16* __restrict__ ygated) {
    __shared__ u16 Ss[128][136];
    __shared__ float clav[64];
    int bid = blockIdx.x;
    int b = bid >> 10, c = (bid >> 5) & 31, hh = bid & 31;
    int tid = threadIdx.x, lane = tid & 63, w = tid >> 6;
    int r = lane & 15, q = lane >> 4;
    int t0 = b * 2048 + c * 64;
    int sbase = ((b * 32 + hh) * 32 + c) * 64;
    size_t sb = ((size_t)((b * 32 + hh) * 32 + c)) * 16384;

    if (tid < 64) clav[tid] = fexp(cumla[sbase + tid]);
    for (int e = tid; e < 2048; e += 256) {
        int p = e >> 4, n8 = (e & 15) * 8;
        *reinterpret_cast<uint4*>(&Ss[p][n8]) =
            *reinterpret_cast<const uint4*>(states + sb + p * 128 + n8);
    }
    __syncthreads();

    const u16* crow = proj + (size_t)(t0 + w * 16 + r) * 8480 + 8352;
    bf16x8 af[4];
#pragma unroll
    for (int k = 0; k < 4; ++k) af[k] = ld8(crow + k * 32 + q * 8);
#pragma unroll
    for (int tj = 0; tj < 8; ++tj) {
        f32x4 acc = (f32x4){0.f, 0.f, 0.f, 0.f};
#pragma unroll
        for (int k = 0; k < 4; ++k)
            acc = __builtin_amdgcn_mfma_f32_16x16x32_bf16(af[k], ld8(&Ss[tj * 16 + r][k * 32 + q * 8]), acc, 0, 0, 0);
        int p = tj * 16 + r;
        int ch = hh * 128 + p;
#pragma unroll
        for (int rg = 0; rg < 4; ++rg) {
            int i = w * 16 + q * 4 + rg;
            size_t td = (size_t)(t0 + i) * 4096 + ch;
            float v = clav[i] * acc[rg] + bf2f(ybuf[td]);
            float g = bf2f(proj[(size_t)(t0 + i) * 8480 + ch]);
            ygated[td] = f2bf(v * (g * frcp(1.f + fexp(-g))));
        }
    }
}

extern "C" void kernel_launch(void* const* d_in, const int* in_sizes, int n_in,
                              void* d_out, int out_size, void* d_ws, size_t ws_size,
                              hipStream_t stream) {
    const float* x          = (const float*)d_in[0];
    const float* norm_scale = (const float*)d_in[1];
    const float* in_proj_w  = (const float*)d_in[2];
    const float* conv_w     = (const float*)d_in[3];
    const float* conv_b     = (const float*)d_in[4];
    const float* A_log      = (const float*)d_in[5];
    const float* dt_bias    = (const float*)d_in[6];
    const float* Dv         = (const float*)d_in[7];
    const float* out_w      = (const float*)d_in[8];
    float* out = (float*)d_out;

    char* ws = (char*)d_ws;
    u16*   states = (u16*)(ws);               // [0,67.1M); h aliases [0,16.8M), wbt [16.8M,52.5M)
    u16*   h      = (u16*)(ws);
    u16*   wbt    = (u16*)(ws + 16777216);    // 8704x2048 bf16 (rows 8480..8703 zero)
    float* parts  = (float*)(ws);             // out-proj split-K partials 2x 4096x2048 f32 (after k_inter)
    u16*   proj   = (u16*)(ws + 67108864);    // 69,468,160
    u16*   owt    = (u16*)(ws + 136577024);   // 2048x4096 bf16
    u16*   ybuf   = (u16*)(ws + 170131456);   // 33,554,432 (also ygated)
    float* tailP  = (float*)(ws + 170131456); // tail partials 4x 4096x384 f32 = 25.2M (pre-intra)
    float* dt     = (float*)(ws + 203685888);
    float* cumla  = (float*)(ws + 204210176);

    // 1: rmsnorm (4096 blocks) ∥ wcast in_proj (4352 blocks)
    k_pre<<<8448, 256, 0, stream>>>(x, norm_scale, h, in_proj_w, wbt);
    // 2: tail split-K GEMM (384 blocks) ∥ wcast out_proj (2048 blocks)
    k_mid<<<2432, 256, 0, stream>>>(h, wbt, tailP, out_w, owt);
    k_tailred<<<1152, 256, 0, stream>>>(tailP, proj);
    // proj main: cols 0..8192, 512 blocks of 256x256 = exactly 2 rounds; ldc=8480
    k_gemm256<false><<<512, 512, 0, stream>>>(h, wbt, proj, nullptr,
                                              4096, 8192, 8480, 2048, 2048);
    k_dt<<<2048, 64, 0, stream>>>(proj, A_log, dt_bias, dt, cumla);
    k_intra<<<2048, 256, 0, stream>>>(proj, dt, cumla, conv_w, conv_b, Dv, ybuf, states);
    k_scan<<<1024, 256, 0, stream>>>(states, cumla);
    k_inter<<<2048, 256, 0, stream>>>(proj, states, cumla, ybuf, ybuf);
    // out-proj: split-K=2, 128 tiles x 2 = 256 blocks = 1 round; f32 partials into parts
    k_gemm256<true><<<256, 512, 0, stream>>>(ybuf, owt, nullptr, parts,
                                             4096, 2048, 2048, 4096, 2048);
    k_addred<<<2048, 256, 0, stream>>>(x, parts, parts + 8388608, out);
}

// Round 11
// 507.888 us; speedup vs baseline: 1.1683x; 1.0090x over previous
//
#include <hip/hip_runtime.h>

typedef unsigned short u16;
typedef unsigned short u16x8 __attribute__((ext_vector_type(8)));
typedef __bf16 bf16x8 __attribute__((ext_vector_type(8)));
typedef float f32x4 __attribute__((ext_vector_type(4)));

// B=2, T=2048, N_EMBD=2048, D_INNER=4096, N_HEADS=32, HEAD_DIM=128, D_STATE=128,
// PROJ=8480 (= 8192 main + 288 tail), CHUNK=64, n_chunks=32. External fp32; staging bf16.
// proj row: [0,4096) gate | [4096,8192) ssm_in | [8192,8224) dt | [8224,8352) B | [8352,8480) C
// NOTE (R9 lesson): cross-run clock noise is ±10-14%; only within-run dispatch comparisons
// are reliable. Main gemm256 reference: ~139-141 µs @ ~1570 GB/s, MfmaUtil ~41%.

__device__ __forceinline__ float bf2f(u16 u) {
    union { unsigned int i; float f; } v; v.i = ((unsigned int)u) << 16; return v.f;
}
__device__ __forceinline__ u16 f2bf(float f) {
    unsigned int u = __float_as_uint(f);
    u += 0x7fffu + ((u >> 16) & 1u);   // RNE
    return (u16)(u >> 16);
}
__device__ __forceinline__ bf16x8 ld8(const u16* p) {
    return __builtin_bit_cast(bf16x8, *reinterpret_cast<const u16x8*>(p));
}
__device__ __forceinline__ void load_lds16(const u16* g, u16* l) {
    __builtin_amdgcn_global_load_lds(
        (const __attribute__((address_space(1))) unsigned int*)g,
        (__attribute__((address_space(3))) unsigned int*)l, 16, 0, 0);
}
__device__ __forceinline__ float fexp(float x) { return __expf(x); }
__device__ __forceinline__ float frcp(float x) { return __builtin_amdgcn_rcpf(x); }

// ---------------- shared wcast body: fp32 [K][N] -> bf16 [Npad][K], one 64x64 tile ----------------
__device__ __forceinline__ void wcast_tile(const float* __restrict__ W, u16* __restrict__ Wt,
                                           int K, int N, int n0, int k0, int t,
                                           u16 (*Ts)[72]) {
    int jl = (t & 15) * 4;
#pragma unroll
    for (int s = 0; s < 4; ++s) {
        int kl = s * 16 + (t >> 4);
        if (n0 + jl + 4 <= N) {
            float4 v = *reinterpret_cast<const float4*>(W + (size_t)(k0 + kl) * N + n0 + jl);
            Ts[kl][jl] = f2bf(v.x); Ts[kl][jl + 1] = f2bf(v.y);
            Ts[kl][jl + 2] = f2bf(v.z); Ts[kl][jl + 3] = f2bf(v.w);
        } else {
#pragma unroll
            for (int e = 0; e < 4; ++e)
                Ts[kl][jl + e] = (n0 + jl + e < N) ? f2bf(W[(size_t)(k0 + kl) * N + n0 + jl + e]) : (u16)0;
        }
    }
    __syncthreads();
    int nl = t >> 2, kl0 = (t & 3) * 16;
    u16 tmp[16];
#pragma unroll
    for (int e = 0; e < 16; ++e) tmp[e] = Ts[kl0 + e][nl];
    u16* dst = Wt + (size_t)(n0 + nl) * K + k0 + kl0;
    *reinterpret_cast<uint4*>(dst) = *reinterpret_cast<uint4*>(tmp);
    *reinterpret_cast<uint4*>(dst + 8) = *reinterpret_cast<uint4*>(tmp + 8);
}

// ---------------- K_pre: rmsnorm (blocks 0..4095) ∥ wcast in_proj (blocks 4096..8447) ----------------
__global__ __launch_bounds__(256) void k_pre(const float* __restrict__ x,
                                             const float* __restrict__ scale,
                                             u16* __restrict__ h,
                                             const float* __restrict__ W,
                                             u16* __restrict__ Wt) {
    __shared__ __align__(16) char smem[9216];
    int bid = blockIdx.x, tid = threadIdx.x;
    if (bid < 4096) {
        // RMSNorm row
        float* red = reinterpret_cast<float*>(smem);
        const float4* xr = reinterpret_cast<const float4*>(x + (size_t)bid * 2048);
        float4 v0 = xr[tid], v1 = xr[tid + 256];
        float ss = v0.x*v0.x + v0.y*v0.y + v0.z*v0.z + v0.w*v0.w
                 + v1.x*v1.x + v1.y*v1.y + v1.z*v1.z + v1.w*v1.w;
#pragma unroll
        for (int off = 32; off > 0; off >>= 1) ss += __shfl_down(ss, off, 64);
        if ((tid & 63) == 0) red[tid >> 6] = ss;
        __syncthreads();
        float r = rsqrtf((red[0] + red[1] + red[2] + red[3]) * (1.f / 2048.f) + 1e-6f);
        const float4* sc = reinterpret_cast<const float4*>(scale);
        float4 s0 = sc[tid], s1 = sc[tid + 256];
        ushort4 o0, o1;
        o0.x = f2bf(v0.x * r * s0.x); o0.y = f2bf(v0.y * r * s0.y);
        o0.z = f2bf(v0.z * r * s0.z); o0.w = f2bf(v0.w * r * s0.w);
        o1.x = f2bf(v1.x * r * s1.x); o1.y = f2bf(v1.y * r * s1.y);
        o1.z = f2bf(v1.z * r * s1.z); o1.w = f2bf(v1.w * r * s1.w);
        ushort4* hr = reinterpret_cast<ushort4*>(h + (size_t)bid * 2048);
        hr[tid] = o0; hr[tid + 256] = o1;
    } else {
        int wb = bid - 4096;                       // 4352 = 136 n-tiles x 32 k-tiles
        int n0 = (wb % 136) * 64, k0 = (wb / 136) * 64;
        wcast_tile(W, Wt, 2048, 8480, n0, k0, tid, reinterpret_cast<u16(*)[72]>(smem));
    }
}

// ---------------- K_mid: split-K tail GEMM (blocks 0..383) ∥ wcast out_proj (384..2431) ------------
// tail: f32 partials Pf[4][M][384] (dense stride 384); Bt rows 8192..8575 zero-padded past 8480.
__global__ __launch_bounds__(256) void k_mid(const u16* __restrict__ A,
                                             const u16* __restrict__ Bt,
                                             float* __restrict__ Pf,
                                             const float* __restrict__ W,
                                             u16* __restrict__ Wt) {
    __shared__ __align__(16) u16 smem[16384];      // tail: As | Bs ; wcast: Ts[64][72]
    int bid = blockIdx.x, t = threadIdx.x;
    if (bid >= 384) {
        int wb = bid - 384;                        // 2048 = 32 n-tiles x 64 k-tiles
        int n0 = (wb % 32) * 64, k0 = (wb / 32) * 64;
        wcast_tile(W, Wt, 4096, 2048, n0, k0, t, reinterpret_cast<u16(*)[72]>(smem));
        return;
    }
    u16* As = smem;
    u16* Bs = smem + 8192;
    const int lda = 2048, Ks = 512, M = 4096, ncoff = 8192;
    int nb = bid % 3;
    int ksl = (bid / 3) & 3;
    int mb = bid / 12;
    int m0 = mb * 128, n0 = nb * 128;
    int koff = ksl * Ks;

    int lane = t & 63, w = t >> 6;
    int row = t >> 2, kc = (t & 3) * 8;
    int wm = (w >> 1) * 64, wn = (w & 1) * 64;
    int r = lane & 15, q = lane >> 4;

    f32x4 acc[4][4];
#pragma unroll
    for (int a = 0; a < 4; ++a)
#pragma unroll
        for (int b = 0; b < 4; ++b) acc[a][b] = (f32x4){0.f, 0.f, 0.f, 0.f};

    const u16* ga0 = A + (size_t)(m0 + row) * lda + koff + kc;
    const u16* ga1 = A + (size_t)(m0 + 64 + row) * lda + koff + kc;
    const u16* gb0 = Bt + (size_t)(ncoff + n0 + row) * lda + koff + kc;
    const u16* gb1 = Bt + (size_t)(ncoff + n0 + 64 + row) * lda + koff + kc;

    for (int k0 = 0; k0 < Ks; k0 += 64) {
        load_lds16(ga0 + k0,      As + w * 512);
        load_lds16(ga1 + k0,      As + 2048 + w * 512);
        load_lds16(gb0 + k0,      Bs + w * 512);
        load_lds16(gb1 + k0,      Bs + 2048 + w * 512);
        load_lds16(ga0 + k0 + 32, As + 4096 + w * 512);
        load_lds16(ga1 + k0 + 32, As + 4096 + 2048 + w * 512);
        load_lds16(gb0 + k0 + 32, Bs + 4096 + w * 512);
        load_lds16(gb1 + k0 + 32, Bs + 4096 + 2048 + w * 512);
        __syncthreads();
#pragma unroll
        for (int hh = 0; hh < 2; ++hh) {
            bf16x8 af[4], bf[4];
#pragma unroll
            for (int mi = 0; mi < 4; ++mi) af[mi] = ld8(&As[hh * 4096 + (wm + mi * 16 + r) * 32 + q * 8]);
#pragma unroll
            for (int ni = 0; ni < 4; ++ni) bf[ni] = ld8(&Bs[hh * 4096 + (wn + ni * 16 + r) * 32 + q * 8]);
#pragma unroll
            for (int mi = 0; mi < 4; ++mi)
#pragma unroll
                for (int ni = 0; ni < 4; ++ni)
                    acc[mi][ni] = __builtin_amdgcn_mfma_f32_16x16x32_bf16(af[mi], bf[ni], acc[mi][ni], 0, 0, 0);
        }
        __syncthreads();
    }
#pragma unroll
    for (int mi = 0; mi < 4; ++mi)
#pragma unroll
        for (int ni = 0; ni < 4; ++ni) {
            int lgn = n0 + wn + ni * 16 + r;
#pragma unroll
            for (int rg = 0; rg < 4; ++rg) {
                int gm = m0 + wm + mi * 16 + q * 4 + rg;
                Pf[((size_t)ksl * M + gm) * 384 + lgn] = acc[mi][ni][rg];
            }
        }
}

// ---------------- K_dtred: tail reduce (blocks 0..1151) + dt/cumla (blocks 1152..1663) -------------
// tailred: sum 4 f32 partials -> proj cols [8192,8480) bf16.
// dt: reads f32 tail partials DIRECTLY (col hh of the 384-wide tail = dt col), computes
//     softplus + per-chunk cumsum of A*dt. More accurate than reading bf16 proj cols.
__global__ __launch_bounds__(256) void k_dtred(const float* __restrict__ Pf,
                                               u16* __restrict__ proj,
                                               const float* __restrict__ A_log,
                                               const float* __restrict__ dt_bias,
                                               float* __restrict__ dt,
                                               float* __restrict__ cumla) {
    int bid = blockIdx.x, tid = threadIdx.x;
    if (bid < 1152) {
        int gid = bid * 256 + tid;                 // 4096 rows * 72 float4 = 294912
        int rowi = gid / 72, c4 = (gid % 72) * 4;
        const float4* P = reinterpret_cast<const float4*>(Pf);
        int idx = rowi * 96 + (c4 >> 2);
        float4 s0 = P[idx], s1 = P[393216 + idx], s2 = P[786432 + idx], s3 = P[1179648 + idx];
        ushort4 o;
        o.x = f2bf(s0.x + s1.x + s2.x + s3.x);
        o.y = f2bf(s0.y + s1.y + s2.y + s3.y);
        o.z = f2bf(s0.z + s1.z + s2.z + s3.z);
        o.w = f2bf(s0.w + s1.w + s2.w + s3.w);
        *reinterpret_cast<ushort4*>(proj + (size_t)rowi * 8480 + 8192 + c4) = o;
        return;
    }
    // dt path: 512 blocks x 4 units (one wave each)
    int unit = (bid - 1152) * 4 + (tid >> 6);      // 2048 units = b(2) x h(32) x c(32)
    int j = tid & 63;
    int b = unit >> 10, hh = (unit >> 5) & 31, c = unit & 31;
    int row = b * 2048 + c * 64 + j;
    float z = Pf[(size_t)row * 384 + hh]
            + Pf[(size_t)(4096 + row) * 384 + hh]
            + Pf[(size_t)(8192 + row) * 384 + hh]
            + Pf[(size_t)(12288 + row) * 384 + hh] + dt_bias[hh];
    float dtv = (z > 20.f) ? z : log1pf(fexp(z));
    float v = -fexp(A_log[hh]) * dtv;
#pragma unroll
    for (int off = 1; off < 64; off <<= 1) {
        float pv = __shfl_up(v, off, 64);
        if (j >= off) v += pv;
    }
    int base = ((b * 32 + hh) * 32 + c) * 64;
    dt[base + j] = dtv;
    cumla[base + j] = v;
}

// ---------------- K2new: 256x256 8-phase GEMM — R2/R5/R7/R10-PROVEN sync structure ----
// 512 thr = 8 waves (2M x 4N); per-wave 128x64 out; BK=64; LDS 128 KiB double-buffered.
// LDS swizzle: 16B-chunk c at row rw holds logical chunk c ^ (rw & 7) (both sides).
// Stage schedule per tile kt (harness-verified R2+R5+R7+R10; R6 full-tile-ahead regressed,
// reverted): p0: A1(kt+1) | p2: B0(kt+2) | p3: B1(kt+2), A0(kt+2), barrier, MFMA, vmcnt(6).
// PARTIAL=true: split-K bf16 partial at Cb + ks*M*Nout (dense); else bf16 at ldc stride.
// lda = row stride of A/Bt (out-proj: lda=4096, Kl=2048). DO NOT EDIT sync (m152).
template <bool PARTIAL>
__global__ __launch_bounds__(512, 2) void k_gemm256(const u16* __restrict__ A,
                                                    const u16* __restrict__ Bt,
                                                    u16* __restrict__ Cb,
                                                    int M, int Nout, int ldc,
                                                    int lda, int Kl) {
    __shared__ u16 lds[65536];          // A: [2buf][2half][128][64] at 0; B same at 32768
    const int nkt = Kl >> 6;
    int mt = M >> 8;
    int bid = blockIdx.x;
    int swz = (bid & 7) * ((int)gridDim.x >> 3) + (bid >> 3);   // XCD-contiguous (grid%8==0)
    int tiles = mt * (Nout >> 8);
    int tp = swz % tiles, ks = swz / tiles;
    int mb = tp % mt, nb = tp / mt;
    int m0 = mb << 8, n0 = nb << 8;
    int koff = ks * Kl;

    int t = threadIdx.x;
    int ln = t & 63, w = t >> 6;
    int wm = w >> 2, wn = w & 3;
    int r = ln & 15, q = ln >> 4;
    int xq = (q << 3) ^ ((r & 7) << 3);          // swizzled chunk offset within row

    // staging: lane covers row (w*8 + ln/8) of the region; source chunk pre-swizzled
    int rr = ln >> 3;
    int cc8 = ((ln & 7) ^ rr) << 3;
    const u16* Ag = A + (size_t)(m0 + w * 8 + rr) * lda + koff + cc8;
    const u16* Bg = Bt + (size_t)(n0 + w * 8 + rr) * lda + koff + cc8;
    u16* ldsw = lds + (w << 9);
    const size_t R64 = (size_t)lda * 64;     // +64 rows
    const size_t R128 = (size_t)lda * 128;   // +128 rows

    f32x4 acc[8][4];
#pragma unroll
    for (int a = 0; a < 8; ++a)
#pragma unroll
        for (int b = 0; b < 4; ++b) acc[a][b] = (f32x4){0.f, 0.f, 0.f, 0.f};

    auto stageA = [&](int ti, int h) {
        if (ti >= nkt) return;
        const u16* g = Ag + ((size_t)ti << 6) + (h ? R128 : (size_t)0);
        u16* d = ldsw + ((ti & 1) << 14) + (h << 13);
        load_lds16(g, d);
        load_lds16(g + R64, d + 4096);
    };
    auto stageB = [&](int ti, int h) {
        if (ti >= nkt) return;
        const u16* g = Bg + ((size_t)ti << 6) + (h ? R128 : (size_t)0);
        u16* d = ldsw + 32768 + ((ti & 1) << 14) + (h << 13);
        load_lds16(g, d);
        load_lds16(g + R64, d + 4096);
    };

    // prologue: S[0..6] = A0(0) B0(0) B1(0) A1(0) A0(1) B0(1) B1(1); vmcnt(6) lands tile 0.
    stageA(0, 0); stageB(0, 0); stageB(0, 1); stageA(0, 1);
    stageA(1, 0); stageB(1, 0); stageB(1, 1);
    asm volatile("s_waitcnt vmcnt(6)" ::: "memory");
    __builtin_amdgcn_s_barrier();
    asm volatile("" ::: "memory");

    bf16x8 aF[4][2], bLo[2][2], bHi[2][2];

    for (int kt = 0; kt < nkt; ++kt) {
        const u16* Ah = lds + ((kt & 1) << 14) + (wm << 13);
        const u16* Bh = lds + 32768 + ((kt & 1) << 14) + ((wn >> 1) << 13) + ((wn & 1) << 12);

        // ---- phase 0: read A-low (8) + B-low (4); stage A1(kt+1); mfma Mlo x Nlo
#pragma unroll
        for (int mi = 0; mi < 4; ++mi)
#pragma unroll
            for (int ks2 = 0; ks2 < 2; ++ks2)
                aF[mi][ks2] = ld8(Ah + (mi * 16 + r) * 64 + (xq ^ (ks2 << 5)));
#pragma unroll
        for (int ni = 0; ni < 2; ++ni)
#pragma unroll
            for (int ks2 = 0; ks2 < 2; ++ks2)
                bLo[ni][ks2] = ld8(Bh + (ni * 16 + r) * 64 + (xq ^ (ks2 << 5)));
        stageA(kt + 1, 1);
        asm volatile("" ::: "memory");
        __builtin_amdgcn_s_barrier();
        asm volatile("s_waitcnt lgkmcnt(0)" ::: "memory");
        __builtin_amdgcn_s_setprio(1);
#pragma unroll
        for (int mi = 0; mi < 4; ++mi)
#pragma unroll
            for (int ni = 0; ni < 2; ++ni)
#pragma unroll
                for (int ks2 = 0; ks2 < 2; ++ks2)
                    acc[mi][ni] = __builtin_amdgcn_mfma_f32_16x16x32_bf16(aF[mi][ks2], bLo[ni][ks2], acc[mi][ni], 0, 0, 0);
        __builtin_amdgcn_s_setprio(0);
        asm volatile("" ::: "memory");
        __builtin_amdgcn_s_barrier();
        asm volatile("" ::: "memory");

        // ---- phase 1: read B-high (4); no stage; mfma Mlo x Nhi
#pragma unroll
        for (int ni = 0; ni < 2; ++ni)
#pragma unroll
            for (int ks2 = 0; ks2 < 2; ++ks2)
                bHi[ni][ks2] = ld8(Bh + ((ni + 2) * 16 + r) * 64 + (xq ^ (ks2 << 5)));
        asm volatile("" ::: "memory");
        __builtin_amdgcn_s_barrier();
        asm volatile("s_waitcnt lgkmcnt(0)" ::: "memory");
        __builtin_amdgcn_s_setprio(1);
#pragma unroll
        for (int mi = 0; mi < 4; ++mi)
#pragma unroll
            for (int ni = 0; ni < 2; ++ni)
#pragma unroll
                for (int ks2 = 0; ks2 < 2; ++ks2)
                    acc[mi][ni + 2] = __builtin_amdgcn_mfma_f32_16x16x32_bf16(aF[mi][ks2], bHi[ni][ks2], acc[mi][ni + 2], 0, 0, 0);
        __builtin_amdgcn_s_setprio(0);
        asm volatile("" ::: "memory");
        __builtin_amdgcn_s_barrier();
        asm volatile("" ::: "memory");

        // ---- phase 2: read A-high (8); stage B0(kt+2); mfma Mhi x Nhi
#pragma unroll
        for (int mi = 0; mi < 4; ++mi)
#pragma unroll
            for (int ks2 = 0; ks2 < 2; ++ks2)
                aF[mi][ks2] = ld8(Ah + ((mi + 4) * 16 + r) * 64 + (xq ^ (ks2 << 5)));
        stageB(kt + 2, 0);
        asm volatile("" ::: "memory");
        __builtin_amdgcn_s_barrier();
        asm volatile("s_waitcnt lgkmcnt(0)" ::: "memory");
        __builtin_amdgcn_s_setprio(1);
#pragma unroll
        for (int mi = 0; mi < 4; ++mi)
#pragma unroll
            for (int ni = 0; ni < 2; ++ni)
#pragma unroll
                for (int ks2 = 0; ks2 < 2; ++ks2)
                    acc[mi + 4][ni + 2] = __builtin_amdgcn_mfma_f32_16x16x32_bf16(aF[mi][ks2], bHi[ni][ks2], acc[mi + 4][ni + 2], 0, 0, 0);
        __builtin_amdgcn_s_setprio(0);
        asm volatile("" ::: "memory");
        __builtin_amdgcn_s_barrier();
        asm volatile("" ::: "memory");

        // ---- phase 3: no reads; stage B1(kt+2) + A0(kt+2); barrier; mfma Mhi x Nlo; vmcnt(6|0)
        stageB(kt + 2, 1);
        stageA(kt + 2, 0);
        asm volatile("" ::: "memory");
        __builtin_amdgcn_s_barrier();
        __builtin_amdgcn_s_setprio(1);
#pragma unroll
        for (int mi = 0; mi < 4; ++mi)
#pragma unroll
            for (int ni = 0; ni < 2; ++ni)
#pragma unroll
                for (int ks2 = 0; ks2 < 2; ++ks2)
                    acc[mi + 4][ni] = __builtin_amdgcn_mfma_f32_16x16x32_bf16(aF[mi][ks2], bLo[ni][ks2], acc[mi + 4][ni], 0, 0, 0);
        __builtin_amdgcn_s_setprio(0);
        if (kt + 2 < nkt) { asm volatile("s_waitcnt vmcnt(6)" ::: "memory"); }
        else              { asm volatile("s_waitcnt vmcnt(0)" ::: "memory"); }
        __builtin_amdgcn_s_barrier();
        asm volatile("" ::: "memory");
    }

    // epilogue: bf16 store — ldc-strided (main) or dense split-K partial (PARTIAL)
#pragma unroll
    for (int mi = 0; mi < 8; ++mi)
#pragma unroll
        for (int ni = 0; ni < 4; ++ni) {
            int gn = n0 + wn * 64 + ni * 16 + r;
            if (gn < Nout) {
#pragma unroll
                for (int rg = 0; rg < 4; ++rg) {
                    int gm = m0 + wm * 128 + mi * 16 + q * 4 + rg;
                    if (PARTIAL) {
                        Cb[(size_t)ks * M * Nout + (size_t)gm * Nout + gn] = f2bf(acc[mi][ni][rg]);
                    } else {
                        Cb[(size_t)gm * ldc + gn] = f2bf(acc[mi][ni][rg]);
                    }
                }
            }
        }
}

// ---------------- K9: out = x + P0 + P1 (bf16 split-K partials + residual) ----------------
__global__ __launch_bounds__(256) void k_addred(const float* __restrict__ x,
                                                const u16* __restrict__ P0,
                                                const u16* __restrict__ P1,
                                                float* __restrict__ out) {
    const float4* xv = reinterpret_cast<const float4*>(x);
    const ushort4* a = reinterpret_cast<const ushort4*>(P0);
    const ushort4* b = reinterpret_cast<const ushort4*>(P1);
    float4* o = reinterpret_cast<float4*>(out);
    for (int k = blockIdx.x * 256 + threadIdx.x; k < 2097152; k += 524288) {
        float4 xx = xv[k]; ushort4 aa = a[k]; ushort4 bb = b[k];
        float4 r;
        r.x = xx.x + bf2f(aa.x) + bf2f(bb.x);
        r.y = xx.y + bf2f(aa.y) + bf2f(bb.y);
        r.z = xx.z + bf2f(aa.z) + bf2f(bb.z);
        r.w = xx.w + bf2f(aa.w) + bf2f(bb.w);
        o[k] = r;
    }
}

// ---------------- K5: intra-chunk, conv+SiLU fused; B/C fragments direct from global ----------------
__global__ __launch_bounds__(256) void k_intra(const u16* __restrict__ proj,
                                               const float* __restrict__ dt,
                                               const float* __restrict__ cumla,
                                               const float* __restrict__ cw,
                                               const float* __restrict__ cb,
                                               const float* __restrict__ Dv,
                                               u16* __restrict__ ybuf,
                                               u16* __restrict__ states) {
    __shared__ u16 Xt[128][72];
    __shared__ u16 Bt[128][72];
    __shared__ union {
        u16 Ms[64][72];                                   // step1 -> step2
        struct { float cwl[4][128]; float cbl[128]; } cv; // staging only
    } sh;
    __shared__ float dts[64], clas[64];
    int bid = blockIdx.x;
    int b = bid >> 10, c = (bid >> 5) & 31, hh = bid & 31;
    int tid = threadIdx.x, lane = tid & 63, w = tid >> 6;
    int r = lane & 15, q = lane >> 4;
    int t0 = b * 2048 + c * 64;
    int sbase = ((b * 32 + hh) * 32 + c) * 64;

    if (tid < 64) { dts[tid] = dt[sbase + tid]; clas[tid] = cumla[sbase + tid]; }
    if (tid < 128) {
        sh.cv.cbl[tid] = cb[hh * 128 + tid];
#pragma unroll
        for (int k = 0; k < 4; ++k) sh.cv.cwl[k][tid] = cw[k * 4096 + hh * 128 + tid];
    }
    __syncthreads();

    // conv(4)+bias+SiLU -> Xt[p][j]; weighted B^T -> Bt[p][j]  (B rows read from global/L2)
    {
        int j = tid & 63;
        float wj = fexp(clas[63] - clas[j]) * dts[j];
        for (int g = tid >> 6; g < 16; g += 4) {
            int p0 = g * 8;
            u16 tb[8];
            *reinterpret_cast<uint4*>(tb) =
                *reinterpret_cast<const uint4*>(proj + (size_t)(t0 + j) * 8480 + 8224 + p0);
            float xv[8];
#pragma unroll
            for (int e = 0; e < 8; ++e) xv[e] = sh.cv.cbl[p0 + e];
#pragma unroll
            for (int kk = 0; kk < 4; ++kk) {
                int tl = c * 64 + j - 3 + kk;
                if (tl >= 0) {
                    u16 srow[8];
                    *reinterpret_cast<uint4*>(srow) =
                        *reinterpret_cast<const uint4*>(proj + (size_t)(b * 2048 + tl) * 8480 + 4096 + hh * 128 + p0);
#pragma unroll
                    for (int e = 0; e < 8; ++e) xv[e] += sh.cv.cwl[kk][p0 + e] * bf2f(srow[e]);
                }
            }
#pragma unroll
            for (int e = 0; e < 8; ++e) {
                float s = xv[e] * frcp(1.f + fexp(-xv[e]));
                Xt[p0 + e][j] = f2bf(s);
                Bt[p0 + e][j] = f2bf(wj * bf2f(tb[e]));
            }
        }
    }
    __syncthreads();

    // step1: M = decay(C·B^T); C and B fragments direct from global (32-head L2 reuse)
    {
        const u16* crow = proj + (size_t)(t0 + w * 16 + r) * 8480 + 8352;
        bf16x8 af[4];
#pragma unroll
        for (int k = 0; k < 4; ++k) af[k] = ld8(crow + k * 32 + q * 8);
#pragma unroll
        for (int tj = 0; tj < 4; ++tj) {
            const u16* brow = proj + (size_t)(t0 + tj * 16 + r) * 8480 + 8224;
            f32x4 acc = (f32x4){0.f, 0.f, 0.f, 0.f};
#pragma unroll
            for (int k = 0; k < 4; ++k)
                acc = __builtin_amdgcn_mfma_f32_16x16x32_bf16(af[k], ld8(brow + k * 32 + q * 8), acc, 0, 0, 0);
            int j = tj * 16 + r;
            float dj = dts[j], cj = clas[j];
#pragma unroll
            for (int rg = 0; rg < 4; ++rg) {
                int i = w * 16 + q * 4 + rg;
                float m = (j <= i) ? acc[rg] * fexp(clas[i] - cj) * dj : 0.f;
                sh.Ms[i][j] = f2bf(m);
            }
        }
    }
    __syncthreads();

    // step2: Y = M @ X + D*X
    {
        bf16x8 af[2];
#pragma unroll
        for (int k = 0; k < 2; ++k) af[k] = ld8(&sh.Ms[w * 16 + r][k * 32 + q * 8]);
#pragma unroll
        for (int tj = 0; tj < 8; ++tj) {
            f32x4 acc = (f32x4){0.f, 0.f, 0.f, 0.f};
#pragma unroll
            for (int k = 0; k < 2; ++k)
                acc = __builtin_amdgcn_mfma_f32_16x16x32_bf16(af[k], ld8(&Xt[tj * 16 + r][k * 32 + q * 8]), acc, 0, 0, 0);
            int p = tj * 16 + r;
            float dv = Dv[hh * 128 + p];
#pragma unroll
            for (int rg = 0; rg < 4; ++rg) {
                int i = w * 16 + q * 4 + rg;
                float v = acc[rg] + dv * bf2f(Xt[p][i]);
                ybuf[(size_t)(t0 + i) * 4096 + hh * 128 + p] = f2bf(v);
            }
        }
    }

    // step3: St[p][n] = sum_j Xt[p][j]*Bt[n][j]
    size_t sb = ((size_t)((b * 32 + hh) * 32 + c)) * 16384;
#pragma unroll
    for (int th = 0; th < 2; ++th) {
        int ti = w + th * 4;
        bf16x8 af[2];
#pragma unroll
        for (int k = 0; k < 2; ++k) af[k] = ld8(&Xt[ti * 16 + r][k * 32 + q * 8]);
#pragma unroll
        for (int tj = 0; tj < 8; ++tj) {
            f32x4 acc = (f32x4){0.f, 0.f, 0.f, 0.f};
#pragma unroll
            for (int k = 0; k < 2; ++k)
                acc = __builtin_amdgcn_mfma_f32_16x16x32_bf16(af[k], ld8(&Bt[tj * 16 + r][k * 32 + q * 8]), acc, 0, 0, 0);
            int n = tj * 16 + r;
#pragma unroll
            for (int rg = 0; rg < 4; ++rg) {
                int p = ti * 16 + q * 4 + rg;
                states[sb + p * 128 + n] = f2bf(acc[rg]);
            }
        }
    }
}

// ---------------- K6: inter-chunk sequential scan, 4 elems/thread (8B vectors) ----------------
__global__ __launch_bounds__(256) void k_scan(u16* __restrict__ states,
                                              const float* __restrict__ cumla) {
    int gid = blockIdx.x * 256 + threadIdx.x;   // 262144 total
    int bh = gid >> 12;
    int q4 = (gid & 4095) * 4;
    size_t base = (size_t)bh * 32 * 16384 + q4;
    float s0 = 0.f, s1 = 0.f, s2 = 0.f, s3 = 0.f;
    for (int c = 0; c < 32; ++c) {
        float cd = fexp(cumla[(bh * 32 + c) * 64 + 63]);
        size_t idx = base + (size_t)c * 16384;
        ushort4 v = *reinterpret_cast<ushort4*>(states + idx);
        float l0 = bf2f(v.x), l1 = bf2f(v.y), l2 = bf2f(v.z), l3 = bf2f(v.w);
        ushort4 o; o.x = f2bf(s0); o.y = f2bf(s1); o.z = f2bf(s2); o.w = f2bf(s3);
        *reinterpret_cast<ushort4*>(states + idx) = o;
        s0 = cd * s0 + l0; s1 = cd * s1 + l1; s2 = cd * s2 + l2; s3 = cd * s3 + l3;
    }
}

// ---------------- K7: Y = ybuf + exp(cla)*C@S, SiLU gate ----------------
__global__ __launch_bounds__(256) void k_inter(const u16* __restrict__ proj,
                                               const u16* __restrict__ states,
                                               const float* __restrict__ cumla,
                                               const u16* __restrict__ ybuf,
                                               u16* __restrict__ ygated) {
    __shared__ u16 Ss[128][136];
    __shared__ float clav[64];
    int bid = blockIdx.x;
    int b = bid >> 10, c = (bid >> 5) & 31, hh = bid & 31;
    int tid = threadIdx.x, lane = tid & 63, w = tid >> 6;
    int r = lane & 15, q = lane >> 4;
    int t0 = b * 2048 + c * 64;
    int sbase = ((b * 32 + hh) * 32 + c) * 64;
    size_t sb = ((size_t)((b * 32 + hh) * 32 + c)) * 16384;

    if (tid < 64) clav[tid] = fexp(cumla[sbase + tid]);
    for (int e = tid; e < 2048; e += 256) {
        int p = e >> 4, n8 = (e & 15) * 8;
        *reinterpret_cast<uint4*>(&Ss[p][n8]) =
            *reinterpret_cast<const uint4*>(states + sb + p * 128 + n8);
    }
    __syncthreads();

    const u16* crow = proj + (size_t)(t0 + w * 16 + r) * 8480 + 8352;
    bf16x8 af[4];
#pragma unroll
    for (int k = 0; k < 4; ++k) af[k] = ld8(crow + k * 32 + q * 8);
#pragma unroll
    for (int tj = 0; tj < 8; ++tj) {
        f32x4 acc = (f32x4){0.f, 0.f, 0.f, 0.f};
#pragma unroll
        for (int k = 0; k < 4; ++k)
            acc = __builtin_amdgcn_mfma_f32_16x16x32_bf16(af[k], ld8(&Ss[tj * 16 + r][k * 32 + q * 8]), acc, 0, 0, 0);
        int p = tj * 16 + r;
        int ch = hh * 128 + p;
#pragma unroll
        for (int rg = 0; rg < 4; ++rg) {
            int i = w * 16 + q * 4 + rg;
            size_t td = (size_t)(t0 + i) * 4096 + ch;
            float v = clav[i] * acc[rg] + bf2f(ybuf[td]);
            float g = bf2f(proj[(size_t)(t0 + i) * 8480 + ch]);
            ygated[td] = f2bf(v * (g * frcp(1.f + fexp(-g))));
        }
    }
}

extern "C" void kernel_launch(void* const* d_in, const int* in_sizes, int n_in,
                              void* d_out, int out_size, void* d_ws, size_t ws_size,
                              hipStream_t stream) {
    const float* x          = (const float*)d_in[0];
    const float* norm_scale = (const float*)d_in[1];
    const float* in_proj_w  = (const float*)d_in[2];
    const float* conv_w     = (const float*)d_in[3];
    const float* conv_b     = (const float*)d_in[4];
    const float* A_log      = (const float*)d_in[5];
    const float* dt_bias    = (const float*)d_in[6];
    const float* Dv         = (const float*)d_in[7];
    const float* out_w      = (const float*)d_in[8];
    float* out = (float*)d_out;

    char* ws = (char*)d_ws;
    u16*   states = (u16*)(ws);               // [0,67.1M); h aliases [0,16.8M), wbt [16.8M,52.5M)
    u16*   h      = (u16*)(ws);
    u16*   wbt    = (u16*)(ws + 16777216);    // 8704x2048 bf16 (rows 8480..8703 zero)
    u16*   parts  = (u16*)(ws);               // out-proj bf16 partials 2x 4096x2048 (after k_inter)
    u16*   proj   = (u16*)(ws + 67108864);    // 69,468,160
    u16*   owt    = (u16*)(ws + 136577024);   // 2048x4096 bf16
    u16*   ybuf   = (u16*)(ws + 170131456);   // 33,554,432 (also ygated)
    float* tailP  = (float*)(ws + 170131456); // tail partials 4x 4096x384 f32 = 25.2M (pre-intra)
    float* dt     = (float*)(ws + 203685888);
    float* cumla  = (float*)(ws + 204210176);

    // 1: rmsnorm (4096 blocks) ∥ wcast in_proj (4352 blocks)
    k_pre<<<8448, 256, 0, stream>>>(x, norm_scale, h, in_proj_w, wbt);
    // 2: tail split-K GEMM (384 blocks) ∥ wcast out_proj (2048 blocks)
    k_mid<<<2432, 256, 0, stream>>>(h, wbt, tailP, out_w, owt);
    // 3: tail reduce -> proj cols 8192..8480 ∥ dt/cumla from f32 tail partials
    k_dtred<<<1664, 256, 0, stream>>>(tailP, proj, A_log, dt_bias, dt, cumla);
    // 4: proj main: cols 0..8192, 512 blocks of 256x256 = exactly 2 rounds; ldc=8480
    k_gemm256<false><<<512, 512, 0, stream>>>(h, wbt, proj, 4096, 8192, 8480, 2048, 2048);
    k_intra<<<2048, 256, 0, stream>>>(proj, dt, cumla, conv_w, conv_b, Dv, ybuf, states);
    k_scan<<<1024, 256, 0, stream>>>(states, cumla);
    k_inter<<<2048, 256, 0, stream>>>(proj, states, cumla, ybuf, ybuf);
    // out-proj: split-K=2, 256 blocks = 1 round; bf16 partials into parts
    k_gemm256<true><<<256, 512, 0, stream>>>(ybuf, owt, parts, 4096, 2048, 2048, 4096, 2048);
    k_addred<<<2048, 256, 0, stream>>>(x, parts, parts + 8388608, out);
}